// Round 2
// baseline (228.546 us; speedup 1.0000x reference)
//
#include <hip/hip_runtime.h>
#include <hip/hip_bf16.h>

// SpikingSelfAttention — round 12: barrier-free k_qkv/k_out.
// B spike tiles are tiny (16KB/step) and L2-resident after the XCD swizzle, so
// LDS staging + per-step __syncthreads was pure overhead. k_qkv/k_out are now
// zero-LDS, zero-barrier dataflow: B fragments loaded per-wave straight from
// global (bit-identical de-swizzled address map -> identical MFMA order),
// A fragments per-ks JIT, s_setprio(1) around MFMA clusters. Compiler
// software-pipelines the fully unrolled DAG with counted vmcnt.
// Numerics unchanged: exact 3-way bf16 weight split; binary spikes.

#define NB 8
#define NC 512
#define NT 4
#define NN 256
#define NL 1024
#define NH 8
#define ND 64
#define BCL (NB*NC*NL)

typedef __attribute__((ext_vector_type(8))) short  short8v;
typedef __attribute__((ext_vector_type(8))) unsigned short us8;
typedef __attribute__((ext_vector_type(4))) unsigned short us4;
typedef __attribute__((ext_vector_type(4))) float f32x4;

__device__ __forceinline__ float bu2f(unsigned short u) {
  return __uint_as_float(((unsigned)u) << 16);
}
__device__ __forceinline__ unsigned short f2bu(float f) {   // RNE f32->bf16
  unsigned b = __float_as_uint(f);
  return (unsigned short)((b + 0x7FFFu + ((b >> 16) & 1u)) >> 16);
}

// ---------------------------------------------------------------------------
// k_prep: blocks [0,512) = weight split into fragment-ordered H2;
//         blocks [512,1024) = proj BN+LIF -> ST0[b][l][c] bf16.
// H2 layout: offset = ((((p*3+j)*4+rt)*8+k0i)*8+chunk)*1024 + r*8
__global__ void k_prep(const float* __restrict__ wq, const float* __restrict__ wk,
                       const float* __restrict__ wv, const float* __restrict__ wp,
                       const float* __restrict__ x,
                       const float* __restrict__ g,  const float* __restrict__ bt,
                       const float* __restrict__ mu, const float* __restrict__ var,
                       unsigned short* __restrict__ H2,
                       unsigned short* __restrict__ ST0) {
  if (blockIdx.x < 512) {
    int gi = blockIdx.x * 256 + threadIdx.x;       // (p,o,k8): 4*512*64
    int p = gi >> 15;
    int o = (gi >> 6) & 511;
    int k8 = gi & 63;
    int rt = o >> 7, r = o & 127;
    int k0i = k8 >> 3, chunk = k8 & 7;
    const float* W = (p == 0) ? wq : (p == 1) ? wk : (p == 2) ? wv : wp;
    const float* src = W + (size_t)o * NC + k8 * 8;
    us8 a[3];
#pragma unroll
    for (int i = 0; i < 8; i++) {
      float w = src[i];
      unsigned short u1 = f2bu(w);
      float r1 = w - bu2f(u1);
      unsigned short u2 = f2bu(r1);
      float r2 = r1 - bu2f(u2);
      unsigned short u3 = f2bu(r2);
      a[0][i] = u1; a[1][i] = u2; a[2][i] = u3;
    }
#pragma unroll
    for (int j = 0; j < 3; j++) {
      size_t off = ((size_t)((((p * 3 + j) * 4 + rt) * 8 + k0i) * 8 + chunk)) * 1024
                   + (size_t)r * 8;
      *(us8*)&H2[off] = a[j];
    }
  } else {
    int bidx = blockIdx.x - 512;
    int b  = bidx >> 6;
    int c0 = (bidx & 63) * 8;
    int n  = threadIdx.x;
    unsigned short spk[NT][8];
#pragma unroll
    for (int i = 0; i < 8; i++) {
      int c = c0 + i;
      float inv = g[c] / sqrtf(var[c] + 1e-5f);
      float m = mu[c], be = bt[c];
      const float* xp = x + ((size_t)(b * NC + c)) * NL + n;
      float v = 0.f;
#pragma unroll
      for (int t = 0; t < NT; t++) {
        float y = (xp[t * NN] - m) * inv + be;
        v = v + (y - v) / 1.5f;
        unsigned short s = 0;
        if (v - 1.0f >= 0.f) { s = 0x3F80; v = 0.f; }
        spk[t][i] = s;
      }
    }
#pragma unroll
    for (int t = 0; t < NT; t++) {
      us8 pk;
#pragma unroll
      for (int i = 0; i < 8; i++) pk[i] = spk[t][i];
      *(us8*)&ST0[((size_t)b * NL + t * NN + n) * NC + c0] = pk;
    }
  }
}

// ---------------------------------------------------------------------------
// Fused q/k/v projection + BN + LIF. 16x16x32 MFMA, 128x128 tile, 4x1 wave
// strips. Barrier-free: B fragments straight from global (L1/L2-resident
// after XCD-grouped swizzle); A fragments JIT per ks; no LDS at all.
__global__ __launch_bounds__(256) void
k_qkv(const unsigned short* __restrict__ H2,
      const unsigned short* __restrict__ ST0,
      const float* __restrict__ gq, const float* __restrict__ bq,
      const float* __restrict__ mq, const float* __restrict__ vq,
      const float* __restrict__ gk, const float* __restrict__ bk,
      const float* __restrict__ mk, const float* __restrict__ vk,
      const float* __restrict__ gv, const float* __restrict__ bv,
      const float* __restrict__ mv, const float* __restrict__ vv,
      unsigned short* __restrict__ STq, unsigned short* __restrict__ STk,
      unsigned short* __restrict__ STv) {
  // XCD-grouped swizzle: id%8 = XCD (round-robin dispatch); each XCD gets a
  // contiguous chunk of the (p,rt,b,n0)-ordered work list so blocks sharing a
  // (p,rt) weight strip co-locate on one XCD's L2.
  int id = blockIdx.x;                  // 768 = 8 xcd * 96 slot
  int xcd = id & 7, slot = id >> 3;
  int qq = xcd * 96 + slot;             // ordered by (p, rt, b, n0)
  int grp = qq >> 6, mi = qq & 63;      // grp = p*4+rt in [0,12)
  int p = grp >> 2, rt = grp & 3;
  int b = mi >> 3;
  int n0 = (mi & 7) * 32;

  int tid = threadIdx.x;
  int w = tid >> 6, lane = tid & 63, quad = lane >> 4, l15 = lane & 15;

  const unsigned short* Sb = ST0 + (size_t)b * NL * NC;
  const unsigned short* Hbase = H2 + ((size_t)((p * 3) * 4 + rt) * 8) * 8192;

  // Per-thread B row offsets for the 8 fragments (jj = nh*4 + t).
  // De-swizzled map of the old LDS path: row = (jj&3)*NN + n0 + (jj>>2)*16 + l15.
  size_t brow[8];
#pragma unroll
  for (int jj = 0; jj < 8; jj++)
    brow[jj] = (size_t)((jj & 3) * NN + n0 + ((jj >> 2) << 4) + l15) * NC
               + (size_t)(quad * 8);

  f32x4 acc[2][8];
#pragma unroll
  for (int ri = 0; ri < 2; ri++)
#pragma unroll
    for (int jj = 0; jj < 8; jj++) acc[ri][jj] = (f32x4){0.f, 0.f, 0.f, 0.f};

#pragma unroll
  for (int k0 = 0; k0 < 8; k0++) {
#pragma unroll
    for (int ks = 0; ks < 2; ks++) {
      short8v bf[8];
#pragma unroll
      for (int jj = 0; jj < 8; jj++)
        bf[jj] = *(const short8v*)&Sb[brow[jj] + k0 * 64 + ks * 32];
      short8v a[3][2];
#pragma unroll
      for (int j = 0; j < 3; j++) {
        const unsigned short* Hj = Hbase + ((size_t)(j * 32 + k0)) * 8192
                                   + (size_t)(ks * 4 + quad) * 1024;
        a[j][0] = *(const short8v*)&Hj[(w * 32 + l15) * 8];
        a[j][1] = *(const short8v*)&Hj[(w * 32 + 16 + l15) * 8];
      }
      __builtin_amdgcn_s_setprio(1);
#pragma unroll
      for (int j = 0; j < 3; j++)
#pragma unroll
        for (int jj = 0; jj < 8; jj++) {
          acc[0][jj] = __builtin_amdgcn_mfma_f32_16x16x32_bf16(
              a[j][0], bf[jj], acc[0][jj], 0, 0, 0);
          acc[1][jj] = __builtin_amdgcn_mfma_f32_16x16x32_bf16(
              a[j][1], bf[jj], acc[1][jj], 0, 0, 0);
        }
      __builtin_amdgcn_s_setprio(0);
    }
  }

  const float *g, *bb, *mpt, *vr;
  unsigned short* So;
  if (p == 0)      { g = gq; bb = bq; mpt = mq; vr = vq; So = STq; }
  else if (p == 1) { g = gk; bb = bk; mpt = mk; vr = vk; So = STk; }
  else             { g = gv; bb = bv; mpt = mv; vr = vv; So = STv; }
  So += (size_t)b * NL * NC;

#pragma unroll
  for (int ri = 0; ri < 2; ri++) {
    int ob = rt * 128 + w * 32 + ri * 16 + quad * 4;
    float av[4], mvv[4], bvv[4];
#pragma unroll
    for (int r = 0; r < 4; r++) {
      av[r]  = g[ob + r] / sqrtf(vr[ob + r] + 1e-5f);
      mvv[r] = mpt[ob + r];
      bvv[r] = bb[ob + r];
    }
#pragma unroll
    for (int nh = 0; nh < 2; nh++) {
      int n = n0 + (nh << 4) + l15;
      unsigned short sp[4][4];          // [t][r]
#pragma unroll
      for (int r = 0; r < 4; r++) {
        float vmem = 0.f;
#pragma unroll
        for (int t = 0; t < NT; t++) {
          float y = (acc[ri][nh * 4 + t][r] - mvv[r]) * av[r] + bvv[r];
          vmem = vmem + (y - vmem) / 1.5f;
          unsigned short s = 0;
          if (vmem - 1.0f >= 0.f) { s = 0x3F80; vmem = 0.f; }
          sp[t][r] = s;
        }
      }
#pragma unroll
      for (int t = 0; t < NT; t++) {
        us4 pk;
#pragma unroll
        for (int r = 0; r < 4; r++) pk[r] = sp[t][r];
        *(us4*)&So[(size_t)(t * NN + n) * NC + ob] = pk;
      }
    }
  }
}

// ---------------------------------------------------------------------------
// Partial Gram: Mpart[ch][bh][e][dd] = sum_{l in 128-chunk} K[l][e]*V[l][dd].
__global__ void k_kvM(const unsigned short* __restrict__ STk,
                      const unsigned short* __restrict__ STv,
                      float* __restrict__ Mpart) {
  int bh = blockIdx.x, ch = blockIdx.y;       // ch 0..7
  int b = bh >> 3, h = bh & 7;
  const unsigned short* Kp = STk + (size_t)b * NL * NC + h * ND;
  const unsigned short* Vp = STv + (size_t)b * NL * NC + h * ND;
  __shared__ float sK[64][72];
  __shared__ float sV[64][72];
  int tid = threadIdx.x, tx = tid & 15, ty = tid >> 4;
  float acc[4][4] = {};
  for (int lt = 0; lt < 2; lt++) {
    int lb = ch * 128 + lt * 64;
#pragma unroll
    for (int i = 0; i < 2; i++) {
      int idx = tid + i * 256;
      int r = idx >> 3, seg = idx & 7;
      us8 kv = *(const us8*)&Kp[(size_t)(lb + r) * NC + seg * 8];
      us8 vv = *(const us8*)&Vp[(size_t)(lb + r) * NC + seg * 8];
#pragma unroll
      for (int q2 = 0; q2 < 8; q2++) {
        sK[r][seg * 8 + q2] = bu2f(kv[q2]);
        sV[r][seg * 8 + q2] = bu2f(vv[q2]);
      }
    }
    __syncthreads();
#pragma unroll 8
    for (int lc = 0; lc < 64; lc++) {
      float kvx[4], vvx[4];
#pragma unroll
      for (int i = 0; i < 4; i++) kvx[i] = sK[lc][ty * 4 + i];
#pragma unroll
      for (int j2 = 0; j2 < 4; j2++) vvx[j2] = sV[lc][tx * 4 + j2];
#pragma unroll
      for (int i = 0; i < 4; i++)
#pragma unroll
        for (int j2 = 0; j2 < 4; j2++)
          acc[i][j2] += kvx[i] * vvx[j2];
    }
    __syncthreads();
  }
  float* Mp = Mpart + ((size_t)ch * 64 + bh) * 4096;
#pragma unroll
  for (int i = 0; i < 4; i++) {
    float4 v4 = make_float4(acc[i][0], acc[i][1], acc[i][2], acc[i][3]);
    *(float4*)&Mp[(ty * 4 + i) * ND + tx * 4] = v4;
  }
}

// ---------------------------------------------------------------------------
// MFMA attention: O^T[dd][l] = sum_e (M1+M2)^T[dd][e] * Q[l][e]; spike O>=12.
// M split into two exact bf16 planes (M integer <=1024 — split exact).
__global__ __launch_bounds__(256) void
k_attn(const unsigned short* __restrict__ STq,
       const float* __restrict__ Mpart,
       unsigned short* __restrict__ STs) {
  __shared__ unsigned short MT1[64 * 64];   // [dd][e], 16B chunks phys = c ^ (dd&7)
  __shared__ unsigned short MT2[64 * 64];
  int lt = blockIdx.x, bh = blockIdx.y;
  int b = bh >> 3, h = bh & 7;
  int tid = threadIdx.x;
  int w = tid >> 6, lane = tid & 63, quad = lane >> 4, l15 = lane & 15;

#pragma unroll
  for (int i = 0; i < 4; i++) {
    int idx4 = tid + i * 256;
    float4 s = ((const float4*)Mpart)[(size_t)bh * 1024 + idx4];
#pragma unroll
    for (int ch = 1; ch < 8; ch++) {
      float4 t = ((const float4*)Mpart)[((size_t)ch * 64 + bh) * 1024 + idx4];
      s.x += t.x; s.y += t.y; s.z += t.z; s.w += t.w;
    }
    int e = idx4 >> 4;
    int dd0 = (idx4 * 4) & 63;
    int chunk = e >> 3;
    float sv[4] = {s.x, s.y, s.z, s.w};
#pragma unroll
    for (int r = 0; r < 4; r++) {
      int dd = dd0 + r;
      unsigned short u1 = f2bu(sv[r]);
      unsigned short u2 = f2bu(sv[r] - bu2f(u1));
      int pos = dd * 64 + (((chunk ^ (dd & 7)) << 3) | (e & 7));
      MT1[pos] = u1;
      MT2[pos] = u2;
    }
  }
  __syncthreads();

  const unsigned short* Qp = STq + (size_t)b * NL * NC + h * ND;
  int lbase = lt * 256 + w * 64;

  f32x4 acc[4][4];                           // [ddtile][ltile]
#pragma unroll
  for (int dt = 0; dt < 4; dt++)
#pragma unroll
    for (int j = 0; j < 4; j++) acc[dt][j] = (f32x4){0.f, 0.f, 0.f, 0.f};

#pragma unroll
  for (int ks = 0; ks < 2; ks++) {
    short8v bq[4];
#pragma unroll
    for (int ltile = 0; ltile < 4; ltile++)
      bq[ltile] = *(const short8v*)&Qp[(size_t)(lbase + ltile * 16 + l15) * NC
                                       + ks * 32 + quad * 8];
    int c8 = ks * 4 + quad;
#pragma unroll
    for (int dt = 0; dt < 4; dt++) {
      int dd = dt * 16 + l15;
      int off = dd * 64 + ((c8 ^ (dd & 7)) << 3);
      short8v a1 = *(const short8v*)&MT1[off];
      short8v a2 = *(const short8v*)&MT2[off];
#pragma unroll
      for (int ltile = 0; ltile < 4; ltile++) {
        acc[dt][ltile] = __builtin_amdgcn_mfma_f32_16x16x32_bf16(a1, bq[ltile], acc[dt][ltile], 0, 0, 0);
        acc[dt][ltile] = __builtin_amdgcn_mfma_f32_16x16x32_bf16(a2, bq[ltile], acc[dt][ltile], 0, 0, 0);
      }
    }
  }

  unsigned short* Sp = STs + (size_t)b * NL * NC + h * ND;
#pragma unroll
  for (int dt = 0; dt < 4; dt++)
#pragma unroll
    for (int ltile = 0; ltile < 4; ltile++) {
      int l = lbase + ltile * 16 + l15;
      int dd = dt * 16 + quad * 4;
      us4 pk;
#pragma unroll
      for (int r = 0; r < 4; r++) pk[r] = (acc[dt][ltile][r] >= 12.0f) ? 0x3F80 : 0;
      *(us4*)&Sp[(size_t)l * NC + dd] = pk;
    }
}

// ---------------------------------------------------------------------------
// Final projection: 16x16x32, 128 rows x 64 cols; barrier-free like k_qkv.
__global__ __launch_bounds__(256) void
k_out(const unsigned short* __restrict__ H2,
      const unsigned short* __restrict__ STs,
      const float* __restrict__ bp, float* __restrict__ out) {
  int id = blockIdx.x;                  // 512 = 8 xcd * 64 slot
  int xcd = id & 7, slot = id >> 3;
  int qq = xcd * 64 + slot;             // ordered by (rt, b, l0)
  int rt = qq >> 7;
  int mi = qq & 127;
  int b  = mi >> 4;
  int l0 = (mi & 15) * 64;

  int tid = threadIdx.x;
  int w = tid >> 6, lane = tid & 63, quad = lane >> 4, l15 = lane & 15;

  const unsigned short* Sb = STs + (size_t)b * NL * NC;
  const unsigned short* Hbase = H2 + ((size_t)(9 * 4 + rt) * 8) * 8192;  // p=3

  size_t brow[4];
#pragma unroll
  for (int jj = 0; jj < 4; jj++)
    brow[jj] = (size_t)(l0 + jj * 16 + l15) * NC + (size_t)(quad * 8);

  f32x4 acc[2][4];
#pragma unroll
  for (int ri = 0; ri < 2; ri++)
#pragma unroll
    for (int jj = 0; jj < 4; jj++) acc[ri][jj] = (f32x4){0.f, 0.f, 0.f, 0.f};

#pragma unroll
  for (int k0 = 0; k0 < 8; k0++) {
#pragma unroll
    for (int ks = 0; ks < 2; ks++) {
      short8v bf[4];
#pragma unroll
      for (int jj = 0; jj < 4; jj++)
        bf[jj] = *(const short8v*)&Sb[brow[jj] + k0 * 64 + ks * 32];
      short8v a[3][2];
#pragma unroll
      for (int j = 0; j < 3; j++) {
        const unsigned short* Hj = Hbase + ((size_t)(j * 32 + k0)) * 8192
                                   + (size_t)(ks * 4 + quad) * 1024;
        a[j][0] = *(const short8v*)&Hj[(w * 32 + l15) * 8];
        a[j][1] = *(const short8v*)&Hj[(w * 32 + 16 + l15) * 8];
      }
      __builtin_amdgcn_s_setprio(1);
#pragma unroll
      for (int j = 0; j < 3; j++)
#pragma unroll
        for (int jj = 0; jj < 4; jj++) {
          acc[0][jj] = __builtin_amdgcn_mfma_f32_16x16x32_bf16(
              a[j][0], bf[jj], acc[0][jj], 0, 0, 0);
          acc[1][jj] = __builtin_amdgcn_mfma_f32_16x16x32_bf16(
              a[j][1], bf[jj], acc[1][jj], 0, 0, 0);
        }
      __builtin_amdgcn_s_setprio(0);
    }
  }

#pragma unroll
  for (int ri = 0; ri < 2; ri++) {
    int ob = rt * 128 + w * 32 + ri * 16 + quad * 4;
#pragma unroll
    for (int jj = 0; jj < 4; jj++) {
      int l = l0 + jj * 16 + l15;
#pragma unroll
      for (int r = 0; r < 4; r++)
        out[((size_t)(b * NC + ob + r)) * NL + l] = acc[ri][jj][r] + bp[ob + r];
    }
  }
}

// ---------------------------------------------------------------------------
extern "C" void kernel_launch(void* const* d_in, const int* in_sizes, int n_in,
                              void* d_out, int out_size, void* d_ws, size_t ws_size,
                              hipStream_t stream) {
  (void)in_sizes; (void)n_in; (void)out_size; (void)ws_size;
  const float* x   = (const float*)d_in[0];
  const float* wq  = (const float*)d_in[1];
  const float* wk  = (const float*)d_in[2];
  const float* wv  = (const float*)d_in[3];
  const float* wp  = (const float*)d_in[4];
  const float* bp  = (const float*)d_in[5];
  const float* gq  = (const float*)d_in[6];
  const float* bq  = (const float*)d_in[7];
  const float* mq  = (const float*)d_in[8];
  const float* vq  = (const float*)d_in[9];
  const float* gk  = (const float*)d_in[10];
  const float* bk  = (const float*)d_in[11];
  const float* mk  = (const float*)d_in[12];
  const float* vk  = (const float*)d_in[13];
  const float* gv  = (const float*)d_in[14];
  const float* bv  = (const float*)d_in[15];
  const float* mv  = (const float*)d_in[16];
  const float* vvv = (const float*)d_in[17];
  const float* gp  = (const float*)d_in[18];
  const float* bpn = (const float*)d_in[19];
  const float* mp  = (const float*)d_in[20];
  const float* vp  = (const float*)d_in[21];

  unsigned short* H2  = (unsigned short*)d_ws;
  unsigned short* ST0 = H2 + (size_t)4 * 3 * NC * NC;
  unsigned short* STq = ST0 + BCL;
  unsigned short* STk = STq + BCL;
  unsigned short* STv = STk + BCL;
  unsigned short* STs = STv + BCL;
  float* Mpart = (float*)(STs + BCL);

  dim3 blk(256);
  k_prep<<<1024, blk, 0, stream>>>(wq, wk, wv, wp, x, gp, bpn, mp, vp, H2, ST0);
  k_qkv<<<768, blk, 0, stream>>>(H2, ST0,
      gq, bq, mq, vq, gk, bk, mk, vk, gv, bv, mv, vvv, STq, STk, STv);
  k_kvM<<<dim3(64, 8), blk, 0, stream>>>(STk, STv, Mpart);
  k_attn<<<dim3(4, 64), blk, 0, stream>>>(STq, Mpart, STs);
  k_out<<<512, blk, 0, stream>>>(H2, STs, bp, (float*)d_out);
}

// Round 3
// 193.225 us; speedup vs baseline: 1.1828x; 1.1828x over previous
//
#include <hip/hip_runtime.h>
#include <hip/hip_bf16.h>

// SpikingSelfAttention — round 13: revert to round-11 LDS-staged structure
// (barrier-free round-12 regressed: uncoalesced per-wave B loads doubled
// FETCH_SIZE). New lever: occupancy. Halve per-block tiles so resident waves
// double — k_qkv 128x64 tiles (1536 blocks, 6/CU, LDS 16KB), k_out 64x64
// tiles (1024 blocks, 4/CU). Same QSTEP schedule, swizzles, and MFMA order
// as round-11 -> bit-identical numerics.
// Numerics: exact 3-way bf16 weight split; binary spikes.

#define NB 8
#define NC 512
#define NT 4
#define NN 256
#define NL 1024
#define NH 8
#define ND 64
#define BCL (NB*NC*NL)

typedef __attribute__((ext_vector_type(8))) short  short8v;
typedef __attribute__((ext_vector_type(8))) unsigned short us8;
typedef __attribute__((ext_vector_type(4))) unsigned short us4;
typedef __attribute__((ext_vector_type(4))) float f32x4;

__device__ __forceinline__ float bu2f(unsigned short u) {
  return __uint_as_float(((unsigned)u) << 16);
}
__device__ __forceinline__ unsigned short f2bu(float f) {   // RNE f32->bf16
  unsigned b = __float_as_uint(f);
  return (unsigned short)((b + 0x7FFFu + ((b >> 16) & 1u)) >> 16);
}

// ---------------------------------------------------------------------------
// k_prep: blocks [0,512) = weight split into fragment-ordered H2;
//         blocks [512,1024) = proj BN+LIF -> ST0[b][l][c] bf16.
// H2 layout: offset = ((((p*3+j)*4+rt)*8+k0i)*8+chunk)*1024 + r*8
__global__ void k_prep(const float* __restrict__ wq, const float* __restrict__ wk,
                       const float* __restrict__ wv, const float* __restrict__ wp,
                       const float* __restrict__ x,
                       const float* __restrict__ g,  const float* __restrict__ bt,
                       const float* __restrict__ mu, const float* __restrict__ var,
                       unsigned short* __restrict__ H2,
                       unsigned short* __restrict__ ST0) {
  if (blockIdx.x < 512) {
    int gi = blockIdx.x * 256 + threadIdx.x;       // (p,o,k8): 4*512*64
    int p = gi >> 15;
    int o = (gi >> 6) & 511;
    int k8 = gi & 63;
    int rt = o >> 7, r = o & 127;
    int k0i = k8 >> 3, chunk = k8 & 7;
    const float* W = (p == 0) ? wq : (p == 1) ? wk : (p == 2) ? wv : wp;
    const float* src = W + (size_t)o * NC + k8 * 8;
    us8 a[3];
#pragma unroll
    for (int i = 0; i < 8; i++) {
      float w = src[i];
      unsigned short u1 = f2bu(w);
      float r1 = w - bu2f(u1);
      unsigned short u2 = f2bu(r1);
      float r2 = r1 - bu2f(u2);
      unsigned short u3 = f2bu(r2);
      a[0][i] = u1; a[1][i] = u2; a[2][i] = u3;
    }
#pragma unroll
    for (int j = 0; j < 3; j++) {
      size_t off = ((size_t)((((p * 3 + j) * 4 + rt) * 8 + k0i) * 8 + chunk)) * 1024
                   + (size_t)r * 8;
      *(us8*)&H2[off] = a[j];
    }
  } else {
    int bidx = blockIdx.x - 512;
    int b  = bidx >> 6;
    int c0 = (bidx & 63) * 8;
    int n  = threadIdx.x;
    unsigned short spk[NT][8];
#pragma unroll
    for (int i = 0; i < 8; i++) {
      int c = c0 + i;
      float inv = g[c] / sqrtf(var[c] + 1e-5f);
      float m = mu[c], be = bt[c];
      const float* xp = x + ((size_t)(b * NC + c)) * NL + n;
      float v = 0.f;
#pragma unroll
      for (int t = 0; t < NT; t++) {
        float y = (xp[t * NN] - m) * inv + be;
        v = v + (y - v) / 1.5f;
        unsigned short s = 0;
        if (v - 1.0f >= 0.f) { s = 0x3F80; v = 0.f; }
        spk[t][i] = s;
      }
    }
#pragma unroll
    for (int t = 0; t < NT; t++) {
      us8 pk;
#pragma unroll
      for (int i = 0; i < 8; i++) pk[i] = spk[t][i];
      *(us8*)&ST0[((size_t)b * NL + t * NN + n) * NC + c0] = pk;
    }
  }
}

// ---------------------------------------------------------------------------
// Fused q/k/v projection + BN + LIF. 16x16x32 MFMA, 128 rows x 64 cols tile,
// 4 waves x 32 rows. XCD-grouped swizzle + A-register double-buffer + LDS
// double-buffered B staging (round-11 schedule, halved tile for occupancy).
__global__ __launch_bounds__(256) void
k_qkv(const unsigned short* __restrict__ H2,
      const unsigned short* __restrict__ ST0,
      const float* __restrict__ gq, const float* __restrict__ bq,
      const float* __restrict__ mq, const float* __restrict__ vq,
      const float* __restrict__ gk, const float* __restrict__ bk,
      const float* __restrict__ mk, const float* __restrict__ vk,
      const float* __restrict__ gv, const float* __restrict__ bv,
      const float* __restrict__ mv, const float* __restrict__ vv,
      unsigned short* __restrict__ STq, unsigned short* __restrict__ STk,
      unsigned short* __restrict__ STv) {
  __shared__ __align__(16) unsigned short sB[2][64 * 64];

  // XCD-grouped swizzle: id%8 = XCD (round-robin dispatch); each XCD gets a
  // contiguous chunk of the (p,rt,b,n0)-ordered work list.
  int id = blockIdx.x;                  // 1536 = 8 xcd * 192 slot
  int xcd = id & 7, slot = id >> 3;
  int qq = xcd * 192 + slot;            // ordered by (p, rt, b, n0)
  int grp = qq >> 7, mi = qq & 127;     // grp = p*4+rt in [0,12)
  int p = grp >> 2, rt = grp & 3;
  int b = mi >> 4;
  int n0 = (mi & 15) * 16;

  int tid = threadIdx.x;
  int w = tid >> 6, lane = tid & 63, quad = lane >> 4, l15 = lane & 15;
  int xorv = l15 & 7;

  const unsigned short* Sb = ST0 + (size_t)b * NL * NC;
  const unsigned short* Hbase = H2 + ((size_t)((p * 3) * 4 + rt) * 8) * 8192;

  f32x4 acc[2][4];
#pragma unroll
  for (int ri = 0; ri < 2; ri++)
#pragma unroll
    for (int jj = 0; jj < 4; jj++) acc[ri][jj] = (f32x4){0.f, 0.f, 0.f, 0.f};

  // A-fragment double-buffer register sets (named, compile-time indexed).
  short8v A0[2][3][2], A1[2][3][2];

#define QLOADA(DST, K0I)                                                     \
  _Pragma("unroll") for (int ks = 0; ks < 2; ks++) {                         \
    int c8 = ks * 4 + quad;                                                  \
    _Pragma("unroll") for (int j = 0; j < 3; j++) {                          \
      const unsigned short* Hj =                                             \
          Hbase + ((size_t)(j * 4 * 8 + (K0I))) * 8192 + (size_t)c8 * 1024;  \
      DST[ks][j][0] = *(const short8v*)&Hj[(w * 32 + l15) * 8];              \
      DST[ks][j][1] = *(const short8v*)&Hj[(w * 32 + 16 + l15) * 8];         \
    }                                                                        \
  }

  QLOADA(A0, 0);                        // prologue A; latency hides under B-stage

  us8 breg[2];
  int ccs[2], segs[2];
  size_t bsrc[2];
#pragma unroll
  for (int i = 0; i < 2; i++) {
    int idx = tid + i * 256;
    int cc = idx >> 3, seg = idx & 7;   // cc = t*16 + nn
    int t = cc >> 4, nn = cc & 15;
    ccs[i] = cc; segs[i] = seg;
    bsrc[i] = (size_t)(t * NN + n0 + nn) * NC + seg * 8;
  }
#pragma unroll
  for (int i = 0; i < 2; i++) breg[i] = *(const us8*)&Sb[bsrc[i]];      // k0=0
#pragma unroll
  for (int i = 0; i < 2; i++)
    *(us8*)&sB[0][ccs[i] * 64 + ((segs[i] ^ (ccs[i] & 7)) << 3)] = breg[i];

#define QBPRE(K0N)                                                           \
  _Pragma("unroll") for (int i = 0; i < 2; i++)                              \
    breg[i] = *(const us8*)&Sb[bsrc[i] + (size_t)(K0N) * 64];

#define QBWRITE(BUFN)                                                        \
  _Pragma("unroll") for (int i = 0; i < 2; i++)                              \
    *(us8*)&sB[BUFN][ccs[i] * 64 + ((segs[i] ^ (ccs[i] & 7)) << 3)] = breg[i];

#define QMFMAS(AR, BUF)                                                      \
  _Pragma("unroll") for (int ks = 0; ks < 2; ks++) {                         \
    int c8 = ks * 4 + quad;                                                  \
    int poff = (c8 ^ xorv) << 3;                                             \
    short8v bf[4];                                                           \
    _Pragma("unroll") for (int jj = 0; jj < 4; jj++)                         \
      bf[jj] = *(const short8v*)&sB[BUF][(jj * 16 + l15) * 64 + poff];       \
    _Pragma("unroll") for (int j = 0; j < 3; j++)                            \
      _Pragma("unroll") for (int jj = 0; jj < 4; jj++) {                     \
        acc[0][jj] = __builtin_amdgcn_mfma_f32_16x16x32_bf16(                \
            AR[ks][j][0], bf[jj], acc[0][jj], 0, 0, 0);                      \
        acc[1][jj] = __builtin_amdgcn_mfma_f32_16x16x32_bf16(                \
            AR[ks][j][1], bf[jj], acc[1][jj], 0, 0, 0);                      \
      }                                                                      \
  }

  // Per step: barrier -> issue NEXT A + NEXT B loads -> MFMA on current A
  // -> stage next B to LDS.
#define QSTEP(K0I, ACUR, ANXT)                                               \
  __syncthreads();                                                           \
  { if ((K0I) < 7) { QLOADA(ANXT, (K0I) + 1); } }                            \
  { if ((K0I) < 7) { QBPRE((K0I) + 1); } }                                   \
  QMFMAS(ACUR, (K0I) & 1);                                                   \
  { if ((K0I) < 7) { QBWRITE(((K0I) & 1) ^ 1); } }

  QSTEP(0, A0, A1)
  QSTEP(1, A1, A0)
  QSTEP(2, A0, A1)
  QSTEP(3, A1, A0)
  QSTEP(4, A0, A1)
  QSTEP(5, A1, A0)
  QSTEP(6, A0, A1)
  QSTEP(7, A1, A0)

#undef QLOADA
#undef QBPRE
#undef QBWRITE
#undef QMFMAS
#undef QSTEP

  const float *g, *bb, *mpt, *vr;
  unsigned short* So;
  if (p == 0)      { g = gq; bb = bq; mpt = mq; vr = vq; So = STq; }
  else if (p == 1) { g = gk; bb = bk; mpt = mk; vr = vk; So = STk; }
  else             { g = gv; bb = bv; mpt = mv; vr = vv; So = STv; }
  So += (size_t)b * NL * NC;

#pragma unroll
  for (int ri = 0; ri < 2; ri++) {
    int ob = rt * 128 + w * 32 + ri * 16 + quad * 4;
    float av[4], mvv[4], bvv[4];
#pragma unroll
    for (int r = 0; r < 4; r++) {
      av[r]  = g[ob + r] / sqrtf(vr[ob + r] + 1e-5f);
      mvv[r] = mpt[ob + r];
      bvv[r] = bb[ob + r];
    }
    int n = n0 + l15;
    unsigned short sp[4][4];            // [t][r]
#pragma unroll
    for (int r = 0; r < 4; r++) {
      float vmem = 0.f;
#pragma unroll
      for (int t = 0; t < NT; t++) {
        float y = (acc[ri][t][r] - mvv[r]) * av[r] + bvv[r];
        vmem = vmem + (y - vmem) / 1.5f;
        unsigned short s = 0;
        if (vmem - 1.0f >= 0.f) { s = 0x3F80; vmem = 0.f; }
        sp[t][r] = s;
      }
    }
#pragma unroll
    for (int t = 0; t < NT; t++) {
      us4 pk;
#pragma unroll
      for (int r = 0; r < 4; r++) pk[r] = sp[t][r];
      *(us4*)&So[(size_t)(t * NN + n) * NC + ob] = pk;
    }
  }
}

// ---------------------------------------------------------------------------
// Partial Gram: Mpart[ch][bh][e][dd] = sum_{l in 128-chunk} K[l][e]*V[l][dd].
__global__ void k_kvM(const unsigned short* __restrict__ STk,
                      const unsigned short* __restrict__ STv,
                      float* __restrict__ Mpart) {
  int bh = blockIdx.x, ch = blockIdx.y;       // ch 0..7
  int b = bh >> 3, h = bh & 7;
  const unsigned short* Kp = STk + (size_t)b * NL * NC + h * ND;
  const unsigned short* Vp = STv + (size_t)b * NL * NC + h * ND;
  __shared__ float sK[64][72];
  __shared__ float sV[64][72];
  int tid = threadIdx.x, tx = tid & 15, ty = tid >> 4;
  float acc[4][4] = {};
  for (int lt = 0; lt < 2; lt++) {
    int lb = ch * 128 + lt * 64;
#pragma unroll
    for (int i = 0; i < 2; i++) {
      int idx = tid + i * 256;
      int r = idx >> 3, seg = idx & 7;
      us8 kv = *(const us8*)&Kp[(size_t)(lb + r) * NC + seg * 8];
      us8 vv = *(const us8*)&Vp[(size_t)(lb + r) * NC + seg * 8];
#pragma unroll
      for (int q2 = 0; q2 < 8; q2++) {
        sK[r][seg * 8 + q2] = bu2f(kv[q2]);
        sV[r][seg * 8 + q2] = bu2f(vv[q2]);
      }
    }
    __syncthreads();
#pragma unroll 8
    for (int lc = 0; lc < 64; lc++) {
      float kvx[4], vvx[4];
#pragma unroll
      for (int i = 0; i < 4; i++) kvx[i] = sK[lc][ty * 4 + i];
#pragma unroll
      for (int j2 = 0; j2 < 4; j2++) vvx[j2] = sV[lc][tx * 4 + j2];
#pragma unroll
      for (int i = 0; i < 4; i++)
#pragma unroll
        for (int j2 = 0; j2 < 4; j2++)
          acc[i][j2] += kvx[i] * vvx[j2];
    }
    __syncthreads();
  }
  float* Mp = Mpart + ((size_t)ch * 64 + bh) * 4096;
#pragma unroll
  for (int i = 0; i < 4; i++) {
    float4 v4 = make_float4(acc[i][0], acc[i][1], acc[i][2], acc[i][3]);
    *(float4*)&Mp[(ty * 4 + i) * ND + tx * 4] = v4;
  }
}

// ---------------------------------------------------------------------------
// MFMA attention: O^T[dd][l] = sum_e (M1+M2)^T[dd][e] * Q[l][e]; spike O>=12.
// M split into two exact bf16 planes (M integer <=1024 — split exact).
__global__ __launch_bounds__(256) void
k_attn(const unsigned short* __restrict__ STq,
       const float* __restrict__ Mpart,
       unsigned short* __restrict__ STs) {
  __shared__ unsigned short MT1[64 * 64];   // [dd][e], 16B chunks phys = c ^ (dd&7)
  __shared__ unsigned short MT2[64 * 64];
  int lt = blockIdx.x, bh = blockIdx.y;
  int b = bh >> 3, h = bh & 7;
  int tid = threadIdx.x;
  int w = tid >> 6, lane = tid & 63, quad = lane >> 4, l15 = lane & 15;

#pragma unroll
  for (int i = 0; i < 4; i++) {
    int idx4 = tid + i * 256;
    float4 s = ((const float4*)Mpart)[(size_t)bh * 1024 + idx4];
#pragma unroll
    for (int ch = 1; ch < 8; ch++) {
      float4 t = ((const float4*)Mpart)[((size_t)ch * 64 + bh) * 1024 + idx4];
      s.x += t.x; s.y += t.y; s.z += t.z; s.w += t.w;
    }
    int e = idx4 >> 4;
    int dd0 = (idx4 * 4) & 63;
    int chunk = e >> 3;
    float sv[4] = {s.x, s.y, s.z, s.w};
#pragma unroll
    for (int r = 0; r < 4; r++) {
      int dd = dd0 + r;
      unsigned short u1 = f2bu(sv[r]);
      unsigned short u2 = f2bu(sv[r] - bu2f(u1));
      int pos = dd * 64 + (((chunk ^ (dd & 7)) << 3) | (e & 7));
      MT1[pos] = u1;
      MT2[pos] = u2;
    }
  }
  __syncthreads();

  const unsigned short* Qp = STq + (size_t)b * NL * NC + h * ND;
  int lbase = lt * 256 + w * 64;

  f32x4 acc[4][4];                           // [ddtile][ltile]
#pragma unroll
  for (int dt = 0; dt < 4; dt++)
#pragma unroll
    for (int j = 0; j < 4; j++) acc[dt][j] = (f32x4){0.f, 0.f, 0.f, 0.f};

#pragma unroll
  for (int ks = 0; ks < 2; ks++) {
    short8v bq[4];
#pragma unroll
    for (int ltile = 0; ltile < 4; ltile++)
      bq[ltile] = *(const short8v*)&Qp[(size_t)(lbase + ltile * 16 + l15) * NC
                                       + ks * 32 + quad * 8];
    int c8 = ks * 4 + quad;
#pragma unroll
    for (int dt = 0; dt < 4; dt++) {
      int dd = dt * 16 + l15;
      int off = dd * 64 + ((c8 ^ (dd & 7)) << 3);
      short8v a1 = *(const short8v*)&MT1[off];
      short8v a2 = *(const short8v*)&MT2[off];
#pragma unroll
      for (int ltile = 0; ltile < 4; ltile++) {
        acc[dt][ltile] = __builtin_amdgcn_mfma_f32_16x16x32_bf16(a1, bq[ltile], acc[dt][ltile], 0, 0, 0);
        acc[dt][ltile] = __builtin_amdgcn_mfma_f32_16x16x32_bf16(a2, bq[ltile], acc[dt][ltile], 0, 0, 0);
      }
    }
  }

  unsigned short* Sp = STs + (size_t)b * NL * NC + h * ND;
#pragma unroll
  for (int dt = 0; dt < 4; dt++)
#pragma unroll
    for (int ltile = 0; ltile < 4; ltile++) {
      int l = lbase + ltile * 16 + l15;
      int dd = dt * 16 + quad * 4;
      us4 pk;
#pragma unroll
      for (int r = 0; r < 4; r++) pk[r] = (acc[dt][ltile][r] >= 12.0f) ? 0x3F80 : 0;
      *(us4*)&Sp[(size_t)l * NC + dd] = pk;
    }
}

// ---------------------------------------------------------------------------
// Final projection: 16x16x32, 64 rows x 64 cols (was 128x64), 4 waves x 16
// rows; XCD-grouped swizzle + A-register double-buffer.
__global__ __launch_bounds__(256) void
k_out(const unsigned short* __restrict__ H2,
      const unsigned short* __restrict__ STs,
      const float* __restrict__ bp, float* __restrict__ out) {
  __shared__ __align__(16) unsigned short sB[2][64 * 64];

  int id = blockIdx.x;                  // 1024 = 8 xcd * 128 slot
  int xcd = id & 7, slot = id >> 3;
  int qq = xcd * 128 + slot;            // ordered by (rt8, b, l0)
  int rt8 = qq >> 7;                    // 64-row strip, 0..7
  int mi = qq & 127;
  int b  = mi >> 4;
  int l0 = (mi & 15) * 64;

  int rtH  = rt8 >> 1;                  // H2's 128-row strip index
  int rsub = (rt8 & 1) * 64;            // row offset within it

  int tid = threadIdx.x;
  int w = tid >> 6, lane = tid & 63, quad = lane >> 4, l15 = lane & 15;
  int xorv = l15 & 7;

  const unsigned short* Sb = STs + (size_t)b * NL * NC;
  const unsigned short* Hbase = H2 + ((size_t)(9 * 4 + rtH) * 8) * 8192;  // p=3

  f32x4 acc4[4];
#pragma unroll
  for (int jj = 0; jj < 4; jj++) acc4[jj] = (f32x4){0.f, 0.f, 0.f, 0.f};

  short8v A0[2][3], A1[2][3];

#define OLOADA(DST, K0I)                                                     \
  _Pragma("unroll") for (int ks = 0; ks < 2; ks++) {                         \
    int c8 = ks * 4 + quad;                                                  \
    _Pragma("unroll") for (int j = 0; j < 3; j++) {                          \
      const unsigned short* Hj =                                             \
          Hbase + ((size_t)(j * 4 * 8 + (K0I))) * 8192 + (size_t)c8 * 1024;  \
      DST[ks][j] = *(const short8v*)&Hj[(rsub + w * 16 + l15) * 8];          \
    }                                                                        \
  }

  OLOADA(A0, 0);

  us8 breg[2];
  int ccs[2], segs[2];
  size_t bsrc[2];
#pragma unroll
  for (int i = 0; i < 2; i++) {
    int idx = tid + i * 256;
    int cc = idx >> 3, seg = idx & 7;
    ccs[i] = cc; segs[i] = seg;
    bsrc[i] = (size_t)(l0 + cc) * NC + seg * 8;
  }
#pragma unroll
  for (int i = 0; i < 2; i++) breg[i] = *(const us8*)&Sb[bsrc[i]];
#pragma unroll
  for (int i = 0; i < 2; i++)
    *(us8*)&sB[0][ccs[i] * 64 + ((segs[i] ^ (ccs[i] & 7)) << 3)] = breg[i];

#define OBPRE(K0N)                                                           \
  _Pragma("unroll") for (int i = 0; i < 2; i++)                              \
    breg[i] = *(const us8*)&Sb[bsrc[i] + (size_t)(K0N) * 64];

#define OBWRITE(BUFN)                                                        \
  _Pragma("unroll") for (int i = 0; i < 2; i++)                              \
    *(us8*)&sB[BUFN][ccs[i] * 64 + ((segs[i] ^ (ccs[i] & 7)) << 3)] = breg[i];

#define OMFMAS(AR, BUF)                                                      \
  _Pragma("unroll") for (int ks = 0; ks < 2; ks++) {                         \
    int c8 = ks * 4 + quad;                                                  \
    int poff = (c8 ^ xorv) << 3;                                             \
    short8v bf[4];                                                           \
    _Pragma("unroll") for (int jj = 0; jj < 4; jj++)                         \
      bf[jj] = *(const short8v*)&sB[BUF][(jj * 16 + l15) * 64 + poff];       \
    _Pragma("unroll") for (int j = 0; j < 3; j++)                            \
      _Pragma("unroll") for (int jj = 0; jj < 4; jj++)                       \
        acc4[jj] = __builtin_amdgcn_mfma_f32_16x16x32_bf16(                  \
            AR[ks][j], bf[jj], acc4[jj], 0, 0, 0);                           \
  }

#define OSTEP(K0I, ACUR, ANXT)                                               \
  __syncthreads();                                                           \
  { if ((K0I) < 7) { OLOADA(ANXT, (K0I) + 1); } }                            \
  { if ((K0I) < 7) { OBPRE((K0I) + 1); } }                                   \
  OMFMAS(ACUR, (K0I) & 1);                                                   \
  { if ((K0I) < 7) { OBWRITE(((K0I) & 1) ^ 1); } }

  OSTEP(0, A0, A1)
  OSTEP(1, A1, A0)
  OSTEP(2, A0, A1)
  OSTEP(3, A1, A0)
  OSTEP(4, A0, A1)
  OSTEP(5, A1, A0)
  OSTEP(6, A0, A1)
  OSTEP(7, A1, A0)

#undef OLOADA
#undef OBPRE
#undef OBWRITE
#undef OMFMAS
#undef OSTEP

  int ob = rt8 * 64 + w * 16 + quad * 4;
#pragma unroll
  for (int jj = 0; jj < 4; jj++) {
    int l = l0 + jj * 16 + l15;
#pragma unroll
    for (int r = 0; r < 4; r++)
      out[((size_t)(b * NC + ob + r)) * NL + l] = acc4[jj][r] + bp[ob + r];
  }
}

// ---------------------------------------------------------------------------
extern "C" void kernel_launch(void* const* d_in, const int* in_sizes, int n_in,
                              void* d_out, int out_size, void* d_ws, size_t ws_size,
                              hipStream_t stream) {
  (void)in_sizes; (void)n_in; (void)out_size; (void)ws_size;
  const float* x   = (const float*)d_in[0];
  const float* wq  = (const float*)d_in[1];
  const float* wk  = (const float*)d_in[2];
  const float* wv  = (const float*)d_in[3];
  const float* wp  = (const float*)d_in[4];
  const float* bp  = (const float*)d_in[5];
  const float* gq  = (const float*)d_in[6];
  const float* bq  = (const float*)d_in[7];
  const float* mq  = (const float*)d_in[8];
  const float* vq  = (const float*)d_in[9];
  const float* gk  = (const float*)d_in[10];
  const float* bk  = (const float*)d_in[11];
  const float* mk  = (const float*)d_in[12];
  const float* vk  = (const float*)d_in[13];
  const float* gv  = (const float*)d_in[14];
  const float* bv  = (const float*)d_in[15];
  const float* mv  = (const float*)d_in[16];
  const float* vvv = (const float*)d_in[17];
  const float* gp  = (const float*)d_in[18];
  const float* bpn = (const float*)d_in[19];
  const float* mp  = (const float*)d_in[20];
  const float* vp  = (const float*)d_in[21];

  unsigned short* H2  = (unsigned short*)d_ws;
  unsigned short* ST0 = H2 + (size_t)4 * 3 * NC * NC;
  unsigned short* STq = ST0 + BCL;
  unsigned short* STk = STq + BCL;
  unsigned short* STv = STk + BCL;
  unsigned short* STs = STv + BCL;
  float* Mpart = (float*)(STs + BCL);

  dim3 blk(256);
  k_prep<<<1024, blk, 0, stream>>>(wq, wk, wv, wp, x, gp, bpn, mp, vp, H2, ST0);
  k_qkv<<<1536, blk, 0, stream>>>(H2, ST0,
      gq, bq, mq, vq, gk, bk, mk, vk, gv, bv, mv, vvv, STq, STk, STv);
  k_kvM<<<dim3(64, 8), blk, 0, stream>>>(STk, STv, Mpart);
  k_attn<<<dim3(4, 64), blk, 0, stream>>>(STq, Mpart, STs);
  k_out<<<1024, blk, 0, stream>>>(H2, STs, bp, (float*)d_out);
}

// Round 4
// 190.065 us; speedup vs baseline: 1.2025x; 1.0166x over previous
//
#include <hip/hip_runtime.h>
#include <hip/hip_bf16.h>

// SpikingSelfAttention — round 14: round-11 structure (best, 185.3us) +
// global_load_lds B-staging. LDS XOR-swizzle moved to the PRODUCER side
// (k_prep pre-swizzles ST0 chunks, k_attn pre-swizzles STs chunks with
// slot = chunk ^ (row&7)), so gload_lds writes linearly and the LDS image is
// bit-identical to round-11 -> identical ds_read/MFMA order/numerics.
// Removes the global->VGPR->ds_write round trip from k_qkv/k_out staging.
// s_setprio(1) wraps MFMA clusters. Numerics: exact 3-way bf16 weight split.

#define NB 8
#define NC 512
#define NT 4
#define NN 256
#define NL 1024
#define NH 8
#define ND 64
#define BCL (NB*NC*NL)

typedef __attribute__((ext_vector_type(8))) short  short8v;
typedef __attribute__((ext_vector_type(8))) unsigned short us8;
typedef __attribute__((ext_vector_type(4))) unsigned short us4;
typedef __attribute__((ext_vector_type(4))) float f32x4;

__device__ __forceinline__ float bu2f(unsigned short u) {
  return __uint_as_float(((unsigned)u) << 16);
}
__device__ __forceinline__ unsigned short f2bu(float f) {   // RNE f32->bf16
  unsigned b = __float_as_uint(f);
  return (unsigned short)((b + 0x7FFFu + ((b >> 16) & 1u)) >> 16);
}
__device__ __forceinline__ void gl16(const void* g, void* l) {
  __builtin_amdgcn_global_load_lds(
      (const __attribute__((address_space(1))) unsigned int*)(g),
      (__attribute__((address_space(3))) unsigned int*)(l), 16, 0, 0);
}

// ---------------------------------------------------------------------------
// k_prep: blocks [0,512) = weight split into fragment-ordered H2;
//         blocks [512,1024) = proj BN+LIF -> ST0[b][l][slot] bf16,
//         chunk j stored at slot j^(n&7) (pre-swizzle for gload_lds staging).
__global__ void k_prep(const float* __restrict__ wq, const float* __restrict__ wk,
                       const float* __restrict__ wv, const float* __restrict__ wp,
                       const float* __restrict__ x,
                       const float* __restrict__ g,  const float* __restrict__ bt,
                       const float* __restrict__ mu, const float* __restrict__ var,
                       unsigned short* __restrict__ H2,
                       unsigned short* __restrict__ ST0) {
  if (blockIdx.x < 512) {
    int gi = blockIdx.x * 256 + threadIdx.x;       // (p,o,k8): 4*512*64
    int p = gi >> 15;
    int o = (gi >> 6) & 511;
    int k8 = gi & 63;
    int rt = o >> 7, r = o & 127;
    int k0i = k8 >> 3, chunk = k8 & 7;
    const float* W = (p == 0) ? wq : (p == 1) ? wk : (p == 2) ? wv : wp;
    const float* src = W + (size_t)o * NC + k8 * 8;
    us8 a[3];
#pragma unroll
    for (int i = 0; i < 8; i++) {
      float w = src[i];
      unsigned short u1 = f2bu(w);
      float r1 = w - bu2f(u1);
      unsigned short u2 = f2bu(r1);
      float r2 = r1 - bu2f(u2);
      unsigned short u3 = f2bu(r2);
      a[0][i] = u1; a[1][i] = u2; a[2][i] = u3;
    }
#pragma unroll
    for (int j = 0; j < 3; j++) {
      size_t off = ((size_t)((((p * 3 + j) * 4 + rt) * 8 + k0i) * 8 + chunk)) * 1024
                   + (size_t)r * 8;
      *(us8*)&H2[off] = a[j];
    }
  } else {
    int bidx = blockIdx.x - 512;
    int b  = bidx >> 6;
    int j  = bidx & 63;                 // full-row chunk index
    int c0 = j * 8;
    int n  = threadIdx.x;
    int slot = j ^ (n & 7);             // pre-swizzle (XOR on low 3 bits only)
    unsigned short spk[NT][8];
#pragma unroll
    for (int i = 0; i < 8; i++) {
      int c = c0 + i;
      float inv = g[c] / sqrtf(var[c] + 1e-5f);
      float m = mu[c], be = bt[c];
      const float* xp = x + ((size_t)(b * NC + c)) * NL + n;
      float v = 0.f;
#pragma unroll
      for (int t = 0; t < NT; t++) {
        float y = (xp[t * NN] - m) * inv + be;
        v = v + (y - v) / 1.5f;
        unsigned short s = 0;
        if (v - 1.0f >= 0.f) { s = 0x3F80; v = 0.f; }
        spk[t][i] = s;
      }
    }
#pragma unroll
    for (int t = 0; t < NT; t++) {
      us8 pk;
#pragma unroll
      for (int i = 0; i < 8; i++) pk[i] = spk[t][i];
      *(us8*)&ST0[((size_t)b * NL + t * NN + n) * NC + slot * 8] = pk;
    }
  }
}

// ---------------------------------------------------------------------------
// Fused q/k/v projection + BN + LIF. 16x16x32 MFMA, 128x128 tile, 4x1 wave
// strips. XCD-grouped swizzle + A-register double-buffer + gload_lds B
// staging (linear dest; source pre-swizzled -> LDS image == round-11).
__global__ __launch_bounds__(256) void
k_qkv(const unsigned short* __restrict__ H2,
      const unsigned short* __restrict__ ST0,
      const float* __restrict__ gq, const float* __restrict__ bq,
      const float* __restrict__ mq, const float* __restrict__ vq,
      const float* __restrict__ gk, const float* __restrict__ bk,
      const float* __restrict__ mk, const float* __restrict__ vk,
      const float* __restrict__ gv, const float* __restrict__ bv,
      const float* __restrict__ mv, const float* __restrict__ vv,
      unsigned short* __restrict__ STq, unsigned short* __restrict__ STk,
      unsigned short* __restrict__ STv) {
  __shared__ __align__(16) unsigned short sB[2][128 * 64];

  int id = blockIdx.x;                  // 768 = 8 xcd * 96 slot
  int xcd = id & 7, slot = id >> 3;
  int qq = xcd * 96 + slot;             // ordered by (p, rt, b, n0)
  int grp = qq >> 6, mi = qq & 63;      // grp = p*4+rt in [0,12)
  int p = grp >> 2, rt = grp & 3;
  int b = mi >> 3;
  int n0 = (mi & 7) * 32;

  int tid = threadIdx.x;
  int w = tid >> 6, lane = tid & 63, quad = lane >> 4, l15 = lane & 15;
  int xorv = l15 & 7;

  const unsigned short* Sb = ST0 + (size_t)b * NL * NC;
  const unsigned short* Hbase = H2 + ((size_t)((p * 3) * 4 + rt) * 8) * 8192;

  f32x4 acc[2][8];
#pragma unroll
  for (int ri = 0; ri < 2; ri++)
#pragma unroll
    for (int jj = 0; jj < 8; jj++) acc[ri][jj] = (f32x4){0.f, 0.f, 0.f, 0.f};

  short8v A0[2][3][2], A1[2][3][2];

#define QLOADA(DST, K0I)                                                     \
  _Pragma("unroll") for (int ks = 0; ks < 2; ks++) {                         \
    int c8 = ks * 4 + quad;                                                  \
    _Pragma("unroll") for (int j = 0; j < 3; j++) {                          \
      const unsigned short* Hj =                                             \
          Hbase + ((size_t)(j * 4 * 8 + (K0I))) * 8192 + (size_t)c8 * 1024;  \
      DST[ks][j][0] = *(const short8v*)&Hj[(w * 32 + l15) * 8];              \
      DST[ks][j][1] = *(const short8v*)&Hj[(w * 32 + 16 + l15) * 8];         \
    }                                                                        \
  }

  // B-staging source offsets: slot-addressed (source pre-swizzled in k_prep).
  size_t bsrc[4];
#pragma unroll
  for (int i = 0; i < 4; i++) {
    int idx = tid + i * 256;
    int cc = idx >> 3, seg = idx & 7;
    int t = (cc >> 4) & 3, nn = (cc & 15) | ((cc >> 6) << 4);
    bsrc[i] = (size_t)(t * NN + n0 + nn) * NC + seg * 8;
  }

#define QSTAGE(K0N, BUFN)                                                    \
  _Pragma("unroll") for (int i = 0; i < 4; i++)                              \
    gl16(&Sb[bsrc[i] + (size_t)(K0N) * 64], &sB[BUFN][(tid + i * 256) * 8]);

  QSTAGE(0, 0);                         // k0=0 tile -> buf0 (async)
  QLOADA(A0, 0);                        // prologue A

#define QMFMAS(AR, BUF)                                                      \
  _Pragma("unroll") for (int ks = 0; ks < 2; ks++) {                         \
    int c8 = ks * 4 + quad;                                                  \
    int poff = (c8 ^ xorv) << 3;                                             \
    short8v bf[8];                                                           \
    _Pragma("unroll") for (int jj = 0; jj < 8; jj++)                         \
      bf[jj] = *(const short8v*)&sB[BUF][(jj * 16 + l15) * 64 + poff];       \
    _Pragma("unroll") for (int j = 0; j < 3; j++)                            \
      _Pragma("unroll") for (int jj = 0; jj < 8; jj++) {                     \
        acc[0][jj] = __builtin_amdgcn_mfma_f32_16x16x32_bf16(                \
            AR[ks][j][0], bf[jj], acc[0][jj], 0, 0, 0);                      \
        acc[1][jj] = __builtin_amdgcn_mfma_f32_16x16x32_bf16(                \
            AR[ks][j][1], bf[jj], acc[1][jj], 0, 0, 0);                      \
      }                                                                      \
  }

  // Per step: barrier (drains prev gloads) -> issue NEXT A + NEXT B-stage ->
  // MFMA on current A/B. Loads have the full MFMA burst to land.
#define QSTEP(K0I, ACUR, ANXT)                                               \
  __syncthreads();                                                           \
  { if ((K0I) < 7) { QLOADA(ANXT, (K0I) + 1); } }                            \
  { if ((K0I) < 7) { QSTAGE((K0I) + 1, ((K0I) & 1) ^ 1); } }                 \
  __builtin_amdgcn_s_setprio(1);                                             \
  QMFMAS(ACUR, (K0I) & 1);                                                   \
  __builtin_amdgcn_s_setprio(0);

  QSTEP(0, A0, A1)
  QSTEP(1, A1, A0)
  QSTEP(2, A0, A1)
  QSTEP(3, A1, A0)
  QSTEP(4, A0, A1)
  QSTEP(5, A1, A0)
  QSTEP(6, A0, A1)
  QSTEP(7, A1, A0)

#undef QLOADA
#undef QSTAGE
#undef QMFMAS
#undef QSTEP

  const float *g, *bb, *mpt, *vr;
  unsigned short* So;
  if (p == 0)      { g = gq; bb = bq; mpt = mq; vr = vq; So = STq; }
  else if (p == 1) { g = gk; bb = bk; mpt = mk; vr = vk; So = STk; }
  else             { g = gv; bb = bv; mpt = mv; vr = vv; So = STv; }
  So += (size_t)b * NL * NC;

#pragma unroll
  for (int ri = 0; ri < 2; ri++) {
    int ob = rt * 128 + w * 32 + ri * 16 + quad * 4;
    float av[4], mvv[4], bvv[4];
#pragma unroll
    for (int r = 0; r < 4; r++) {
      av[r]  = g[ob + r] / sqrtf(vr[ob + r] + 1e-5f);
      mvv[r] = mpt[ob + r];
      bvv[r] = bb[ob + r];
    }
#pragma unroll
    for (int nh = 0; nh < 2; nh++) {
      int n = n0 + (nh << 4) + l15;
      unsigned short sp[4][4];          // [t][r]
#pragma unroll
      for (int r = 0; r < 4; r++) {
        float vmem = 0.f;
#pragma unroll
        for (int t = 0; t < NT; t++) {
          float y = (acc[ri][nh * 4 + t][r] - mvv[r]) * av[r] + bvv[r];
          vmem = vmem + (y - vmem) / 1.5f;
          unsigned short s = 0;
          if (vmem - 1.0f >= 0.f) { s = 0x3F80; vmem = 0.f; }
          sp[t][r] = s;
        }
      }
#pragma unroll
      for (int t = 0; t < NT; t++) {
        us4 pk;
#pragma unroll
        for (int r = 0; r < 4; r++) pk[r] = sp[t][r];
        *(us4*)&So[(size_t)(t * NN + n) * NC + ob] = pk;
      }
    }
  }
}

// ---------------------------------------------------------------------------
// Partial Gram: Mpart[ch][bh][e][dd] = sum_{l in 128-chunk} K[l][e]*V[l][dd].
__global__ void k_kvM(const unsigned short* __restrict__ STk,
                      const unsigned short* __restrict__ STv,
                      float* __restrict__ Mpart) {
  int bh = blockIdx.x, ch = blockIdx.y;       // ch 0..7
  int b = bh >> 3, h = bh & 7;
  const unsigned short* Kp = STk + (size_t)b * NL * NC + h * ND;
  const unsigned short* Vp = STv + (size_t)b * NL * NC + h * ND;
  __shared__ float sK[64][72];
  __shared__ float sV[64][72];
  int tid = threadIdx.x, tx = tid & 15, ty = tid >> 4;
  float acc[4][4] = {};
  for (int lt = 0; lt < 2; lt++) {
    int lb = ch * 128 + lt * 64;
#pragma unroll
    for (int i = 0; i < 2; i++) {
      int idx = tid + i * 256;
      int r = idx >> 3, seg = idx & 7;
      us8 kv = *(const us8*)&Kp[(size_t)(lb + r) * NC + seg * 8];
      us8 vv = *(const us8*)&Vp[(size_t)(lb + r) * NC + seg * 8];
#pragma unroll
      for (int q2 = 0; q2 < 8; q2++) {
        sK[r][seg * 8 + q2] = bu2f(kv[q2]);
        sV[r][seg * 8 + q2] = bu2f(vv[q2]);
      }
    }
    __syncthreads();
#pragma unroll 8
    for (int lc = 0; lc < 64; lc++) {
      float kvx[4], vvx[4];
#pragma unroll
      for (int i = 0; i < 4; i++) kvx[i] = sK[lc][ty * 4 + i];
#pragma unroll
      for (int j2 = 0; j2 < 4; j2++) vvx[j2] = sV[lc][tx * 4 + j2];
#pragma unroll
      for (int i = 0; i < 4; i++)
#pragma unroll
        for (int j2 = 0; j2 < 4; j2++)
          acc[i][j2] += kvx[i] * vvx[j2];
    }
    __syncthreads();
  }
  float* Mp = Mpart + ((size_t)ch * 64 + bh) * 4096;
#pragma unroll
  for (int i = 0; i < 4; i++) {
    float4 v4 = make_float4(acc[i][0], acc[i][1], acc[i][2], acc[i][3]);
    *(float4*)&Mp[(ty * 4 + i) * ND + tx * 4] = v4;
  }
}

// ---------------------------------------------------------------------------
// MFMA attention: O^T[dd][l] = sum_e (M1+M2)^T[dd][e] * Q[l][e]; spike O>=12.
// M split into two exact bf16 planes. STs written PRE-SWIZZLED for k_out:
// 16B chunk c of row l stored at slot c^(l&7).
__global__ __launch_bounds__(256) void
k_attn(const unsigned short* __restrict__ STq,
       const float* __restrict__ Mpart,
       unsigned short* __restrict__ STs) {
  __shared__ unsigned short MT1[64 * 64];   // [dd][e], 16B chunks phys = c ^ (dd&7)
  __shared__ unsigned short MT2[64 * 64];
  int lt = blockIdx.x, bh = blockIdx.y;
  int b = bh >> 3, h = bh & 7;
  int tid = threadIdx.x;
  int w = tid >> 6, lane = tid & 63, quad = lane >> 4, l15 = lane & 15;

#pragma unroll
  for (int i = 0; i < 4; i++) {
    int idx4 = tid + i * 256;
    float4 s = ((const float4*)Mpart)[(size_t)bh * 1024 + idx4];
#pragma unroll
    for (int ch = 1; ch < 8; ch++) {
      float4 t = ((const float4*)Mpart)[((size_t)ch * 64 + bh) * 1024 + idx4];
      s.x += t.x; s.y += t.y; s.z += t.z; s.w += t.w;
    }
    int e = idx4 >> 4;
    int dd0 = (idx4 * 4) & 63;
    int chunk = e >> 3;
    float sv[4] = {s.x, s.y, s.z, s.w};
#pragma unroll
    for (int r = 0; r < 4; r++) {
      int dd = dd0 + r;
      unsigned short u1 = f2bu(sv[r]);
      unsigned short u2 = f2bu(sv[r] - bu2f(u1));
      int pos = dd * 64 + (((chunk ^ (dd & 7)) << 3) | (e & 7));
      MT1[pos] = u1;
      MT2[pos] = u2;
    }
  }
  __syncthreads();

  const unsigned short* Qp = STq + (size_t)b * NL * NC + h * ND;
  int lbase = lt * 256 + w * 64;

  f32x4 acc[4][4];                           // [ddtile][ltile]
#pragma unroll
  for (int dt = 0; dt < 4; dt++)
#pragma unroll
    for (int j = 0; j < 4; j++) acc[dt][j] = (f32x4){0.f, 0.f, 0.f, 0.f};

#pragma unroll
  for (int ks = 0; ks < 2; ks++) {
    short8v bq[4];
#pragma unroll
    for (int ltile = 0; ltile < 4; ltile++)
      bq[ltile] = *(const short8v*)&Qp[(size_t)(lbase + ltile * 16 + l15) * NC
                                       + ks * 32 + quad * 8];
    int c8 = ks * 4 + quad;
#pragma unroll
    for (int dt = 0; dt < 4; dt++) {
      int dd = dt * 16 + l15;
      int off = dd * 64 + ((c8 ^ (dd & 7)) << 3);
      short8v a1 = *(const short8v*)&MT1[off];
      short8v a2 = *(const short8v*)&MT2[off];
#pragma unroll
      for (int ltile = 0; ltile < 4; ltile++) {
        acc[dt][ltile] = __builtin_amdgcn_mfma_f32_16x16x32_bf16(a1, bq[ltile], acc[dt][ltile], 0, 0, 0);
        acc[dt][ltile] = __builtin_amdgcn_mfma_f32_16x16x32_bf16(a2, bq[ltile], acc[dt][ltile], 0, 0, 0);
      }
    }
  }

  unsigned short* Sp = STs + (size_t)b * NL * NC;
#pragma unroll
  for (int dt = 0; dt < 4; dt++)
#pragma unroll
    for (int ltile = 0; ltile < 4; ltile++) {
      int l = lbase + ltile * 16 + l15;
      int colshort = h * ND + dt * 16 + quad * 4;
      int chunk = colshort >> 3;        // h*8 + dt*2 + (quad>>1)
      int half  = colshort & 7;         // 0 or 4
      int slt = chunk ^ (l & 7);        // pre-swizzle for k_out staging
      us4 pk;
#pragma unroll
      for (int r = 0; r < 4; r++) pk[r] = (acc[dt][ltile][r] >= 12.0f) ? 0x3F80 : 0;
      *(us4*)&Sp[(size_t)l * NC + (slt << 3) + half] = pk;
    }
}

// ---------------------------------------------------------------------------
// Final projection: 16x16x32, 128 rows x 64 cols; XCD-grouped swizzle +
// A-register double-buffer + gload_lds B staging (source pre-swizzled in
// k_attn -> LDS image identical to round-11).
__global__ __launch_bounds__(256) void
k_out(const unsigned short* __restrict__ H2,
      const unsigned short* __restrict__ STs,
      const float* __restrict__ bp, float* __restrict__ out) {
  __shared__ __align__(16) unsigned short sB[2][64 * 64];

  int id = blockIdx.x;                  // 512 = 8 xcd * 64 slot
  int xcd = id & 7, slot = id >> 3;
  int qq = xcd * 64 + slot;             // ordered by (rt, b, l0)
  int rt = qq >> 7;
  int mi = qq & 127;
  int b  = mi >> 4;
  int l0 = (mi & 15) * 64;

  int tid = threadIdx.x;
  int w = tid >> 6, lane = tid & 63, quad = lane >> 4, l15 = lane & 15;
  int xorv = l15 & 7;

  const unsigned short* Sb = STs + (size_t)b * NL * NC;
  const unsigned short* Hbase = H2 + ((size_t)(9 * 4 + rt) * 8) * 8192;  // p=3

  f32x4 acc[2][4];
#pragma unroll
  for (int ri = 0; ri < 2; ri++)
#pragma unroll
    for (int jj = 0; jj < 4; jj++) acc[ri][jj] = (f32x4){0.f, 0.f, 0.f, 0.f};

  short8v A0[2][3][2], A1[2][3][2];

#define OLOADA(DST, K0I)                                                     \
  _Pragma("unroll") for (int ks = 0; ks < 2; ks++) {                         \
    int c8 = ks * 4 + quad;                                                  \
    _Pragma("unroll") for (int j = 0; j < 3; j++) {                          \
      const unsigned short* Hj =                                             \
          Hbase + ((size_t)(j * 4 * 8 + (K0I))) * 8192 + (size_t)c8 * 1024;  \
      DST[ks][j][0] = *(const short8v*)&Hj[(w * 32 + l15) * 8];              \
      DST[ks][j][1] = *(const short8v*)&Hj[(w * 32 + 16 + l15) * 8];         \
    }                                                                        \
  }

  size_t bsrc[2];
#pragma unroll
  for (int i = 0; i < 2; i++) {
    int idx = tid + i * 256;
    bsrc[i] = (size_t)(l0 + (idx >> 3)) * NC + (idx & 7) * 8;
  }

#define OSTAGE(K0N, BUFN)                                                    \
  _Pragma("unroll") for (int i = 0; i < 2; i++)                              \
    gl16(&Sb[bsrc[i] + (size_t)(K0N) * 64], &sB[BUFN][(tid + i * 256) * 8]);

  OSTAGE(0, 0);
  OLOADA(A0, 0);

#define OMFMAS(AR, BUF)                                                      \
  _Pragma("unroll") for (int ks = 0; ks < 2; ks++) {                         \
    int c8 = ks * 4 + quad;                                                  \
    int poff = (c8 ^ xorv) << 3;                                             \
    short8v bf[4];                                                           \
    _Pragma("unroll") for (int jj = 0; jj < 4; jj++)                         \
      bf[jj] = *(const short8v*)&sB[BUF][(jj * 16 + l15) * 64 + poff];       \
    _Pragma("unroll") for (int j = 0; j < 3; j++)                            \
      _Pragma("unroll") for (int jj = 0; jj < 4; jj++) {                     \
        acc[0][jj] = __builtin_amdgcn_mfma_f32_16x16x32_bf16(                \
            AR[ks][j][0], bf[jj], acc[0][jj], 0, 0, 0);                      \
        acc[1][jj] = __builtin_amdgcn_mfma_f32_16x16x32_bf16(                \
            AR[ks][j][1], bf[jj], acc[1][jj], 0, 0, 0);                      \
      }                                                                      \
  }

#define OSTEP(K0I, ACUR, ANXT)                                               \
  __syncthreads();                                                           \
  { if ((K0I) < 7) { OLOADA(ANXT, (K0I) + 1); } }                            \
  { if ((K0I) < 7) { OSTAGE((K0I) + 1, ((K0I) & 1) ^ 1); } }                 \
  __builtin_amdgcn_s_setprio(1);                                             \
  OMFMAS(ACUR, (K0I) & 1);                                                   \
  __builtin_amdgcn_s_setprio(0);

  OSTEP(0, A0, A1)
  OSTEP(1, A1, A0)
  OSTEP(2, A0, A1)
  OSTEP(3, A1, A0)
  OSTEP(4, A0, A1)
  OSTEP(5, A1, A0)
  OSTEP(6, A0, A1)
  OSTEP(7, A1, A0)

#undef OLOADA
#undef OSTAGE
#undef OMFMAS
#undef OSTEP

#pragma unroll
  for (int ri = 0; ri < 2; ri++) {
    int ob = rt * 128 + w * 32 + ri * 16 + quad * 4;
#pragma unroll
    for (int jj = 0; jj < 4; jj++) {
      int l = l0 + jj * 16 + l15;
#pragma unroll
      for (int r = 0; r < 4; r++)
        out[((size_t)(b * NC + ob + r)) * NL + l] = acc[ri][jj][r] + bp[ob + r];
    }
  }
}

// ---------------------------------------------------------------------------
extern "C" void kernel_launch(void* const* d_in, const int* in_sizes, int n_in,
                              void* d_out, int out_size, void* d_ws, size_t ws_size,
                              hipStream_t stream) {
  (void)in_sizes; (void)n_in; (void)out_size; (void)ws_size;
  const float* x   = (const float*)d_in[0];
  const float* wq  = (const float*)d_in[1];
  const float* wk  = (const float*)d_in[2];
  const float* wv  = (const float*)d_in[3];
  const float* wp  = (const float*)d_in[4];
  const float* bp  = (const float*)d_in[5];
  const float* gq  = (const float*)d_in[6];
  const float* bq  = (const float*)d_in[7];
  const float* mq  = (const float*)d_in[8];
  const float* vq  = (const float*)d_in[9];
  const float* gk  = (const float*)d_in[10];
  const float* bk  = (const float*)d_in[11];
  const float* mk  = (const float*)d_in[12];
  const float* vk  = (const float*)d_in[13];
  const float* gv  = (const float*)d_in[14];
  const float* bv  = (const float*)d_in[15];
  const float* mv  = (const float*)d_in[16];
  const float* vvv = (const float*)d_in[17];
  const float* gp  = (const float*)d_in[18];
  const float* bpn = (const float*)d_in[19];
  const float* mp  = (const float*)d_in[20];
  const float* vp  = (const float*)d_in[21];

  unsigned short* H2  = (unsigned short*)d_ws;
  unsigned short* ST0 = H2 + (size_t)4 * 3 * NC * NC;
  unsigned short* STq = ST0 + BCL;
  unsigned short* STk = STq + BCL;
  unsigned short* STv = STk + BCL;
  unsigned short* STs = STv + BCL;
  float* Mpart = (float*)(STs + BCL);

  dim3 blk(256);
  k_prep<<<1024, blk, 0, stream>>>(wq, wk, wv, wp, x, gp, bpn, mp, vp, H2, ST0);
  k_qkv<<<768, blk, 0, stream>>>(H2, ST0,
      gq, bq, mq, vq, gk, bk, mk, vk, gv, bv, mv, vvv, STq, STk, STv);
  k_kvM<<<dim3(64, 8), blk, 0, stream>>>(STk, STv, Mpart);
  k_attn<<<dim3(4, 64), blk, 0, stream>>>(STq, Mpart, STs);
  k_out<<<512, blk, 0, stream>>>(H2, STs, bp, (float*)d_out);
}

// Round 5
// 184.920 us; speedup vs baseline: 1.2359x; 1.0278x over previous
//
#include <hip/hip_runtime.h>
#include <hip/hip_bf16.h>

// SpikingSelfAttention — round 15: revert k_prep/k_qkv-core/k_attn/k_out to
// round-11 (best, 185.3us). New lever: k_kvM Gram via MFMA. k_qkv's epilogue
// writes K and V TRANSPOSED ([c][l]) so both Gram operands are contiguous
// us8 fragment loads; k_kvM becomes LDS-free, 64 MFMA/block. Mpart layout
// unchanged -> k_attn identical. All Gram sums are integers (0/1 spikes),
// fp32-exact in any order -> bit-identical numerics.

#define NB 8
#define NC 512
#define NT 4
#define NN 256
#define NL 1024
#define NH 8
#define ND 64
#define BCL (NB*NC*NL)

typedef __attribute__((ext_vector_type(8))) short  short8v;
typedef __attribute__((ext_vector_type(8))) unsigned short us8;
typedef __attribute__((ext_vector_type(4))) unsigned short us4;
typedef __attribute__((ext_vector_type(4))) float f32x4;

__device__ __forceinline__ float bu2f(unsigned short u) {
  return __uint_as_float(((unsigned)u) << 16);
}
__device__ __forceinline__ unsigned short f2bu(float f) {   // RNE f32->bf16
  unsigned b = __float_as_uint(f);
  return (unsigned short)((b + 0x7FFFu + ((b >> 16) & 1u)) >> 16);
}

// ---------------------------------------------------------------------------
// k_prep: blocks [0,512) = weight split into fragment-ordered H2;
//         blocks [512,1024) = proj BN+LIF -> ST0[b][l][c] bf16.
// H2 layout: offset = ((((p*3+j)*4+rt)*8+k0i)*8+chunk)*1024 + r*8
__global__ void k_prep(const float* __restrict__ wq, const float* __restrict__ wk,
                       const float* __restrict__ wv, const float* __restrict__ wp,
                       const float* __restrict__ x,
                       const float* __restrict__ g,  const float* __restrict__ bt,
                       const float* __restrict__ mu, const float* __restrict__ var,
                       unsigned short* __restrict__ H2,
                       unsigned short* __restrict__ ST0) {
  if (blockIdx.x < 512) {
    int gi = blockIdx.x * 256 + threadIdx.x;       // (p,o,k8): 4*512*64
    int p = gi >> 15;
    int o = (gi >> 6) & 511;
    int k8 = gi & 63;
    int rt = o >> 7, r = o & 127;
    int k0i = k8 >> 3, chunk = k8 & 7;
    const float* W = (p == 0) ? wq : (p == 1) ? wk : (p == 2) ? wv : wp;
    const float* src = W + (size_t)o * NC + k8 * 8;
    us8 a[3];
#pragma unroll
    for (int i = 0; i < 8; i++) {
      float w = src[i];
      unsigned short u1 = f2bu(w);
      float r1 = w - bu2f(u1);
      unsigned short u2 = f2bu(r1);
      float r2 = r1 - bu2f(u2);
      unsigned short u3 = f2bu(r2);
      a[0][i] = u1; a[1][i] = u2; a[2][i] = u3;
    }
#pragma unroll
    for (int j = 0; j < 3; j++) {
      size_t off = ((size_t)((((p * 3 + j) * 4 + rt) * 8 + k0i) * 8 + chunk)) * 1024
                   + (size_t)r * 8;
      *(us8*)&H2[off] = a[j];
    }
  } else {
    int bidx = blockIdx.x - 512;
    int b  = bidx >> 6;
    int c0 = (bidx & 63) * 8;
    int n  = threadIdx.x;
    unsigned short spk[NT][8];
#pragma unroll
    for (int i = 0; i < 8; i++) {
      int c = c0 + i;
      float inv = g[c] / sqrtf(var[c] + 1e-5f);
      float m = mu[c], be = bt[c];
      const float* xp = x + ((size_t)(b * NC + c)) * NL + n;
      float v = 0.f;
#pragma unroll
      for (int t = 0; t < NT; t++) {
        float y = (xp[t * NN] - m) * inv + be;
        v = v + (y - v) / 1.5f;
        unsigned short s = 0;
        if (v - 1.0f >= 0.f) { s = 0x3F80; v = 0.f; }
        spk[t][i] = s;
      }
    }
#pragma unroll
    for (int t = 0; t < NT; t++) {
      us8 pk;
#pragma unroll
      for (int i = 0; i < 8; i++) pk[i] = spk[t][i];
      *(us8*)&ST0[((size_t)b * NL + t * NN + n) * NC + c0] = pk;
    }
  }
}

// ---------------------------------------------------------------------------
// Fused q/k/v projection + BN + LIF. 16x16x32 MFMA, 128x128 tile, 4x1 wave
// strips. XCD-grouped swizzle + A-register double-buffer (round-11 core).
// Epilogue: q written normal [l][c] (STq); k,v written TRANSPOSED [c][l]
// (STkT/STvT) to feed the MFMA Gram kernel with contiguous fragments.
__global__ __launch_bounds__(256) void
k_qkv(const unsigned short* __restrict__ H2,
      const unsigned short* __restrict__ ST0,
      const float* __restrict__ gq, const float* __restrict__ bq,
      const float* __restrict__ mq, const float* __restrict__ vq,
      const float* __restrict__ gk, const float* __restrict__ bk,
      const float* __restrict__ mk, const float* __restrict__ vk,
      const float* __restrict__ gv, const float* __restrict__ bv,
      const float* __restrict__ mv, const float* __restrict__ vv,
      unsigned short* __restrict__ STq, unsigned short* __restrict__ STkT,
      unsigned short* __restrict__ STvT) {
  __shared__ __align__(16) unsigned short sB[2][128 * 64];

  int id = blockIdx.x;                  // 768 = 8 xcd * 96 slot
  int xcd = id & 7, slot = id >> 3;
  int qq = xcd * 96 + slot;             // ordered by (p, rt, b, n0)
  int grp = qq >> 6, mi = qq & 63;      // grp = p*4+rt in [0,12)
  int p = grp >> 2, rt = grp & 3;
  int b = mi >> 3;
  int n0 = (mi & 7) * 32;

  int tid = threadIdx.x;
  int w = tid >> 6, lane = tid & 63, quad = lane >> 4, l15 = lane & 15;
  int xorv = l15 & 7;

  const unsigned short* Sb = ST0 + (size_t)b * NL * NC;
  const unsigned short* Hbase = H2 + ((size_t)((p * 3) * 4 + rt) * 8) * 8192;

  f32x4 acc[2][8];
#pragma unroll
  for (int ri = 0; ri < 2; ri++)
#pragma unroll
    for (int jj = 0; jj < 8; jj++) acc[ri][jj] = (f32x4){0.f, 0.f, 0.f, 0.f};

  // A-fragment double-buffer register sets (named, compile-time indexed).
  short8v A0[2][3][2], A1[2][3][2];

#define QLOADA(DST, K0I)                                                     \
  _Pragma("unroll") for (int ks = 0; ks < 2; ks++) {                         \
    int c8 = ks * 4 + quad;                                                  \
    _Pragma("unroll") for (int j = 0; j < 3; j++) {                          \
      const unsigned short* Hj =                                             \
          Hbase + ((size_t)(j * 4 * 8 + (K0I))) * 8192 + (size_t)c8 * 1024;  \
      DST[ks][j][0] = *(const short8v*)&Hj[(w * 32 + l15) * 8];              \
      DST[ks][j][1] = *(const short8v*)&Hj[(w * 32 + 16 + l15) * 8];         \
    }                                                                        \
  }

  QLOADA(A0, 0);                        // prologue A; latency hides under B-stage

  us8 breg[4];
  int ccs[4], segs[4];
  size_t bsrc[4];
#pragma unroll
  for (int i = 0; i < 4; i++) {
    int idx = tid + i * 256;
    int cc = idx >> 3, seg = idx & 7;
    int t = (cc >> 4) & 3, nn = (cc & 15) | ((cc >> 6) << 4);
    ccs[i] = cc; segs[i] = seg;
    bsrc[i] = (size_t)(t * NN + n0 + nn) * NC + seg * 8;
  }
#pragma unroll
  for (int i = 0; i < 4; i++) breg[i] = *(const us8*)&Sb[bsrc[i]];      // k0=0
#pragma unroll
  for (int i = 0; i < 4; i++)
    *(us8*)&sB[0][ccs[i] * 64 + ((segs[i] ^ (ccs[i] & 7)) << 3)] = breg[i];

#define QBPRE(K0N)                                                           \
  _Pragma("unroll") for (int i = 0; i < 4; i++)                              \
    breg[i] = *(const us8*)&Sb[bsrc[i] + (size_t)(K0N) * 64];

#define QBWRITE(BUFN)                                                        \
  _Pragma("unroll") for (int i = 0; i < 4; i++)                              \
    *(us8*)&sB[BUFN][ccs[i] * 64 + ((segs[i] ^ (ccs[i] & 7)) << 3)] = breg[i];

#define QMFMAS(AR, BUF)                                                      \
  _Pragma("unroll") for (int ks = 0; ks < 2; ks++) {                         \
    int c8 = ks * 4 + quad;                                                  \
    int poff = (c8 ^ xorv) << 3;                                             \
    short8v bf[8];                                                           \
    _Pragma("unroll") for (int jj = 0; jj < 8; jj++)                         \
      bf[jj] = *(const short8v*)&sB[BUF][(jj * 16 + l15) * 64 + poff];       \
    _Pragma("unroll") for (int j = 0; j < 3; j++)                            \
      _Pragma("unroll") for (int jj = 0; jj < 8; jj++) {                     \
        acc[0][jj] = __builtin_amdgcn_mfma_f32_16x16x32_bf16(                \
            AR[ks][j][0], bf[jj], acc[0][jj], 0, 0, 0);                      \
        acc[1][jj] = __builtin_amdgcn_mfma_f32_16x16x32_bf16(                \
            AR[ks][j][1], bf[jj], acc[1][jj], 0, 0, 0);                      \
      }                                                                      \
  }

  // Per step: barrier -> issue NEXT A + NEXT B loads -> MFMA on current A
  // (hides next-A latency under current MFMA burst) -> stage next B to LDS.
#define QSTEP(K0I, ACUR, ANXT)                                               \
  __syncthreads();                                                           \
  { if ((K0I) < 7) { QLOADA(ANXT, (K0I) + 1); } }                            \
  { if ((K0I) < 7) { QBPRE((K0I) + 1); } }                                   \
  QMFMAS(ACUR, (K0I) & 1);                                                   \
  { if ((K0I) < 7) { QBWRITE(((K0I) & 1) ^ 1); } }

  QSTEP(0, A0, A1)
  QSTEP(1, A1, A0)
  QSTEP(2, A0, A1)
  QSTEP(3, A1, A0)
  QSTEP(4, A0, A1)
  QSTEP(5, A1, A0)
  QSTEP(6, A0, A1)
  QSTEP(7, A1, A0)

#undef QLOADA
#undef QBPRE
#undef QBWRITE
#undef QMFMAS
#undef QSTEP

  const float *g, *bb, *mpt, *vr;
  unsigned short* So;
  if (p == 0)      { g = gq; bb = bq; mpt = mq; vr = vq; So = STq; }
  else if (p == 1) { g = gk; bb = bk; mpt = mk; vr = vk; So = STkT; }
  else             { g = gv; bb = bv; mpt = mv; vr = vv; So = STvT; }
  So += (size_t)b * NL * NC;            // same byte offset for both layouts

#pragma unroll
  for (int ri = 0; ri < 2; ri++) {
    int ob = rt * 128 + w * 32 + ri * 16 + quad * 4;
    float av[4], mvv[4], bvv[4];
#pragma unroll
    for (int r = 0; r < 4; r++) {
      av[r]  = g[ob + r] / sqrtf(vr[ob + r] + 1e-5f);
      mvv[r] = mpt[ob + r];
      bvv[r] = bb[ob + r];
    }
#pragma unroll
    for (int nh = 0; nh < 2; nh++) {
      int n = n0 + (nh << 4) + l15;
      unsigned short sp[4][4];          // [t][r]
#pragma unroll
      for (int r = 0; r < 4; r++) {
        float vmem = 0.f;
#pragma unroll
        for (int t = 0; t < NT; t++) {
          float y = (acc[ri][nh * 4 + t][r] - mvv[r]) * av[r] + bvv[r];
          vmem = vmem + (y - vmem) / 1.5f;
          unsigned short s = 0;
          if (vmem - 1.0f >= 0.f) { s = 0x3F80; vmem = 0.f; }
          sp[t][r] = s;
        }
      }
      if (p == 0) {
#pragma unroll
        for (int t = 0; t < NT; t++) {
          us4 pk;
#pragma unroll
          for (int r = 0; r < 4; r++) pk[r] = sp[t][r];
          *(us4*)&So[(size_t)(t * NN + n) * NC + ob] = pk;
        }
      } else {
        // transposed [c][l]: c = ob+r, l = t*NN+n
#pragma unroll
        for (int t = 0; t < NT; t++)
#pragma unroll
          for (int r = 0; r < 4; r++)
            So[(size_t)(ob + r) * NL + t * NN + n] = sp[t][r];
      }
    }
  }
}

// ---------------------------------------------------------------------------
// MFMA Gram: Mpart[ch][bh][e][dd] = sum_{l in 128-chunk} K[l][e]*V[l][dd].
// KT/VT are [c][l] -> both fragments are contiguous us8 loads; LDS-free.
// All products/sums are integers (spikes 0/1) -> fp32-exact, order-free.
__global__ __launch_bounds__(256) void
k_kvM(const unsigned short* __restrict__ STkT,
      const unsigned short* __restrict__ STvT,
      float* __restrict__ Mpart) {
  int bh = blockIdx.x, ch = blockIdx.y;       // ch 0..7
  int b = bh >> 3, h = bh & 7;
  const unsigned short* KT = STkT + ((size_t)(b * NC + h * ND)) * NL;
  const unsigned short* VT = STvT + ((size_t)(b * NC + h * ND)) * NL;
  int tid = threadIdx.x;
  int w = tid >> 6, lane = tid & 63, quad = lane >> 4, l15 = lane & 15;
  int lb = ch * 128;

  f32x4 acc[4];
#pragma unroll
  for (int jj = 0; jj < 4; jj++) acc[jj] = (f32x4){0.f, 0.f, 0.f, 0.f};

#pragma unroll
  for (int ks = 0; ks < 4; ks++) {
    int lc = lb + ks * 32 + quad * 8;
    short8v a = *(const short8v*)&KT[(size_t)(w * 16 + l15) * NL + lc];
#pragma unroll
    for (int jj = 0; jj < 4; jj++) {
      short8v bv = *(const short8v*)&VT[(size_t)(jj * 16 + l15) * NL + lc];
      acc[jj] = __builtin_amdgcn_mfma_f32_16x16x32_bf16(a, bv, acc[jj], 0, 0, 0);
    }
  }

  float* Mp = Mpart + ((size_t)ch * 64 + bh) * 4096;
#pragma unroll
  for (int jj = 0; jj < 4; jj++)
#pragma unroll
    for (int r = 0; r < 4; r++)
      Mp[(w * 16 + quad * 4 + r) * ND + jj * 16 + l15] = acc[jj][r];
}

// ---------------------------------------------------------------------------
// MFMA attention: O^T[dd][l] = sum_e (M1+M2)^T[dd][e] * Q[l][e]; spike O>=12.
// M split into two exact bf16 planes (M integer <=1024 — split exact).
__global__ __launch_bounds__(256) void
k_attn(const unsigned short* __restrict__ STq,
       const float* __restrict__ Mpart,
       unsigned short* __restrict__ STs) {
  __shared__ unsigned short MT1[64 * 64];   // [dd][e], 16B chunks phys = c ^ (dd&7)
  __shared__ unsigned short MT2[64 * 64];
  int lt = blockIdx.x, bh = blockIdx.y;
  int b = bh >> 3, h = bh & 7;
  int tid = threadIdx.x;
  int w = tid >> 6, lane = tid & 63, quad = lane >> 4, l15 = lane & 15;

#pragma unroll
  for (int i = 0; i < 4; i++) {
    int idx4 = tid + i * 256;
    float4 s = ((const float4*)Mpart)[(size_t)bh * 1024 + idx4];
#pragma unroll
    for (int ch = 1; ch < 8; ch++) {
      float4 t = ((const float4*)Mpart)[((size_t)ch * 64 + bh) * 1024 + idx4];
      s.x += t.x; s.y += t.y; s.z += t.z; s.w += t.w;
    }
    int e = idx4 >> 4;
    int dd0 = (idx4 * 4) & 63;
    int chunk = e >> 3;
    float sv[4] = {s.x, s.y, s.z, s.w};
#pragma unroll
    for (int r = 0; r < 4; r++) {
      int dd = dd0 + r;
      unsigned short u1 = f2bu(sv[r]);
      unsigned short u2 = f2bu(sv[r] - bu2f(u1));
      int pos = dd * 64 + (((chunk ^ (dd & 7)) << 3) | (e & 7));
      MT1[pos] = u1;
      MT2[pos] = u2;
    }
  }
  __syncthreads();

  const unsigned short* Qp = STq + (size_t)b * NL * NC + h * ND;
  int lbase = lt * 256 + w * 64;

  f32x4 acc[4][4];                           // [ddtile][ltile]
#pragma unroll
  for (int dt = 0; dt < 4; dt++)
#pragma unroll
    for (int j = 0; j < 4; j++) acc[dt][j] = (f32x4){0.f, 0.f, 0.f, 0.f};

#pragma unroll
  for (int ks = 0; ks < 2; ks++) {
    short8v bq[4];
#pragma unroll
    for (int ltile = 0; ltile < 4; ltile++)
      bq[ltile] = *(const short8v*)&Qp[(size_t)(lbase + ltile * 16 + l15) * NC
                                       + ks * 32 + quad * 8];
    int c8 = ks * 4 + quad;
#pragma unroll
    for (int dt = 0; dt < 4; dt++) {
      int dd = dt * 16 + l15;
      int off = dd * 64 + ((c8 ^ (dd & 7)) << 3);
      short8v a1 = *(const short8v*)&MT1[off];
      short8v a2 = *(const short8v*)&MT2[off];
#pragma unroll
      for (int ltile = 0; ltile < 4; ltile++) {
        acc[dt][ltile] = __builtin_amdgcn_mfma_f32_16x16x32_bf16(a1, bq[ltile], acc[dt][ltile], 0, 0, 0);
        acc[dt][ltile] = __builtin_amdgcn_mfma_f32_16x16x32_bf16(a2, bq[ltile], acc[dt][ltile], 0, 0, 0);
      }
    }
  }

  unsigned short* Sp = STs + (size_t)b * NL * NC + h * ND;
#pragma unroll
  for (int dt = 0; dt < 4; dt++)
#pragma unroll
    for (int ltile = 0; ltile < 4; ltile++) {
      int l = lbase + ltile * 16 + l15;
      int dd = dt * 16 + quad * 4;
      us4 pk;
#pragma unroll
      for (int r = 0; r < 4; r++) pk[r] = (acc[dt][ltile][r] >= 12.0f) ? 0x3F80 : 0;
      *(us4*)&Sp[(size_t)l * NC + dd] = pk;
    }
}

// ---------------------------------------------------------------------------
// Final projection: 16x16x32, 128 rows x 64 cols; XCD-grouped swizzle +
// A-register double-buffer (round-11 version).
__global__ __launch_bounds__(256) void
k_out(const unsigned short* __restrict__ H2,
      const unsigned short* __restrict__ STs,
      const float* __restrict__ bp, float* __restrict__ out) {
  __shared__ __align__(16) unsigned short sB[2][64 * 64];

  int id = blockIdx.x;                  // 512 = 8 xcd * 64 slot
  int xcd = id & 7, slot = id >> 3;
  int qq = xcd * 64 + slot;             // ordered by (rt, b, l0)
  int rt = qq >> 7;
  int mi = qq & 127;
  int b  = mi >> 4;
  int l0 = (mi & 15) * 64;

  int tid = threadIdx.x;
  int w = tid >> 6, lane = tid & 63, quad = lane >> 4, l15 = lane & 15;
  int xorv = l15 & 7;

  const unsigned short* Sb = STs + (size_t)b * NL * NC;
  const unsigned short* Hbase = H2 + ((size_t)(9 * 4 + rt) * 8) * 8192;  // p=3

  f32x4 acc[2][4];
#pragma unroll
  for (int ri = 0; ri < 2; ri++)
#pragma unroll
    for (int jj = 0; jj < 4; jj++) acc[ri][jj] = (f32x4){0.f, 0.f, 0.f, 0.f};

  short8v A0[2][3][2], A1[2][3][2];

#define OLOADA(DST, K0I)                                                     \
  _Pragma("unroll") for (int ks = 0; ks < 2; ks++) {                         \
    int c8 = ks * 4 + quad;                                                  \
    _Pragma("unroll") for (int j = 0; j < 3; j++) {                          \
      const unsigned short* Hj =                                             \
          Hbase + ((size_t)(j * 4 * 8 + (K0I))) * 8192 + (size_t)c8 * 1024;  \
      DST[ks][j][0] = *(const short8v*)&Hj[(w * 32 + l15) * 8];              \
      DST[ks][j][1] = *(const short8v*)&Hj[(w * 32 + 16 + l15) * 8];         \
    }                                                                        \
  }

  OLOADA(A0, 0);

  us8 breg[2];
  int ccs[2], segs[2];
  size_t bsrc[2];
#pragma unroll
  for (int i = 0; i < 2; i++) {
    int idx = tid + i * 256;
    int cc = idx >> 3, seg = idx & 7;
    ccs[i] = cc; segs[i] = seg;
    bsrc[i] = (size_t)(l0 + cc) * NC + seg * 8;
  }
#pragma unroll
  for (int i = 0; i < 2; i++) breg[i] = *(const us8*)&Sb[bsrc[i]];
#pragma unroll
  for (int i = 0; i < 2; i++)
    *(us8*)&sB[0][ccs[i] * 64 + ((segs[i] ^ (ccs[i] & 7)) << 3)] = breg[i];

#define OBPRE(K0N)                                                           \
  _Pragma("unroll") for (int i = 0; i < 2; i++)                              \
    breg[i] = *(const us8*)&Sb[bsrc[i] + (size_t)(K0N) * 64];

#define OBWRITE(BUFN)                                                        \
  _Pragma("unroll") for (int i = 0; i < 2; i++)                              \
    *(us8*)&sB[BUFN][ccs[i] * 64 + ((segs[i] ^ (ccs[i] & 7)) << 3)] = breg[i];

#define OMFMAS(AR, BUF)                                                      \
  _Pragma("unroll") for (int ks = 0; ks < 2; ks++) {                         \
    int c8 = ks * 4 + quad;                                                  \
    int poff = (c8 ^ xorv) << 3;                                             \
    short8v bf[4];                                                           \
    _Pragma("unroll") for (int jj = 0; jj < 4; jj++)                         \
      bf[jj] = *(const short8v*)&sB[BUF][(jj * 16 + l15) * 64 + poff];       \
    _Pragma("unroll") for (int j = 0; j < 3; j++)                            \
      _Pragma("unroll") for (int jj = 0; jj < 4; jj++) {                     \
        acc[0][jj] = __builtin_amdgcn_mfma_f32_16x16x32_bf16(                \
            AR[ks][j][0], bf[jj], acc[0][jj], 0, 0, 0);                      \
        acc[1][jj] = __builtin_amdgcn_mfma_f32_16x16x32_bf16(                \
            AR[ks][j][1], bf[jj], acc[1][jj], 0, 0, 0);                      \
      }                                                                      \
  }

#define OSTEP(K0I, ACUR, ANXT)                                               \
  __syncthreads();                                                           \
  { if ((K0I) < 7) { OLOADA(ANXT, (K0I) + 1); } }                            \
  { if ((K0I) < 7) { OBPRE((K0I) + 1); } }                                   \
  OMFMAS(ACUR, (K0I) & 1);                                                   \
  { if ((K0I) < 7) { OBWRITE(((K0I) & 1) ^ 1); } }

  OSTEP(0, A0, A1)
  OSTEP(1, A1, A0)
  OSTEP(2, A0, A1)
  OSTEP(3, A1, A0)
  OSTEP(4, A0, A1)
  OSTEP(5, A1, A0)
  OSTEP(6, A0, A1)
  OSTEP(7, A1, A0)

#undef OLOADA
#undef OBPRE
#undef OBWRITE
#undef OMFMAS
#undef OSTEP

#pragma unroll
  for (int ri = 0; ri < 2; ri++) {
    int ob = rt * 128 + w * 32 + ri * 16 + quad * 4;
#pragma unroll
    for (int jj = 0; jj < 4; jj++) {
      int l = l0 + jj * 16 + l15;
#pragma unroll
      for (int r = 0; r < 4; r++)
        out[((size_t)(b * NC + ob + r)) * NL + l] = acc[ri][jj][r] + bp[ob + r];
    }
  }
}

// ---------------------------------------------------------------------------
extern "C" void kernel_launch(void* const* d_in, const int* in_sizes, int n_in,
                              void* d_out, int out_size, void* d_ws, size_t ws_size,
                              hipStream_t stream) {
  (void)in_sizes; (void)n_in; (void)out_size; (void)ws_size;
  const float* x   = (const float*)d_in[0];
  const float* wq  = (const float*)d_in[1];
  const float* wk  = (const float*)d_in[2];
  const float* wv  = (const float*)d_in[3];
  const float* wp  = (const float*)d_in[4];
  const float* bp  = (const float*)d_in[5];
  const float* gq  = (const float*)d_in[6];
  const float* bq  = (const float*)d_in[7];
  const float* mq  = (const float*)d_in[8];
  const float* vq  = (const float*)d_in[9];
  const float* gk  = (const float*)d_in[10];
  const float* bk  = (const float*)d_in[11];
  const float* mk  = (const float*)d_in[12];
  const float* vk  = (const float*)d_in[13];
  const float* gv  = (const float*)d_in[14];
  const float* bv  = (const float*)d_in[15];
  const float* mv  = (const float*)d_in[16];
  const float* vvv = (const float*)d_in[17];
  const float* gp  = (const float*)d_in[18];
  const float* bpn = (const float*)d_in[19];
  const float* mp  = (const float*)d_in[20];
  const float* vp  = (const float*)d_in[21];

  unsigned short* H2   = (unsigned short*)d_ws;
  unsigned short* ST0  = H2 + (size_t)4 * 3 * NC * NC;
  unsigned short* STq  = ST0 + BCL;
  unsigned short* STkT = STq + BCL;
  unsigned short* STvT = STkT + BCL;
  unsigned short* STs  = STvT + BCL;
  float* Mpart = (float*)(STs + BCL);

  dim3 blk(256);
  k_prep<<<1024, blk, 0, stream>>>(wq, wk, wv, wp, x, gp, bpn, mp, vp, H2, ST0);
  k_qkv<<<768, blk, 0, stream>>>(H2, ST0,
      gq, bq, mq, vq, gk, bk, mk, vk, gv, bv, mv, vvv, STq, STkT, STvT);
  k_kvM<<<dim3(64, 8), blk, 0, stream>>>(STkT, STvT, Mpart);
  k_attn<<<dim3(4, 64), blk, 0, stream>>>(STq, Mpart, STs);
  k_out<<<512, blk, 0, stream>>>(H2, STs, bp, (float*)d_out);
}